// Round 9
// baseline (196.277 us; speedup 1.0000x reference)
//
#include <hip/hip_runtime.h>
#include <math.h>

#define BATCH 36
#define H 8
#define L 1152
#define DK 72
#define DM 576
#define LK 128
#define B2 18
#define NC 3

// derived
#define POOL_PER_B (DM*LK)            // 73728
#define POOL_TOTAL (BATCH*POOL_PER_B) // 2654208
#define CLUS_TOTAL (BATCH*LK*B2)      // 82944
#define CCPOOL_PER_B (LK*B2*64)       // 147456
#define CTX_ELEMS (BATCH*H*L*DK)      // 23887872
#define NBH (BATCH*H)                 // 288

typedef __attribute__((ext_vector_type(8))) short short8;
typedef __attribute__((ext_vector_type(4))) float f32x4;

// round-to-nearest-even fp32 -> bf16 bits
__device__ __forceinline__ unsigned short bf16_rne(float x) {
  unsigned u = __float_as_uint(x);
  unsigned r = u + 0x7FFFu + ((u >> 16) & 1u);
  return (unsigned short)(r >> 16);
}
__device__ __forceinline__ unsigned pack2(float a, float b) {
  return (unsigned)bf16_rne(a) | ((unsigned)bf16_rne(b) << 16);
}

// ---------------------------------------------------------------------------
// K1: MaxPool1d(kernel=9, stride=9, pad=4) — register-blocked, zero-LDS,
// persistent grid-stride (8 blocks/CU resident for the whole kernel: removes
// launch ramp/tail that capped the one-shot version at ~72us).
// ---------------------------------------------------------------------------
#define POOL_GROUPS (2 * (BATCH * DM) * 32)   // 1327104
__global__ __launch_bounds__(256) void pool_kernel(
    const float* __restrict__ Kin, const float* __restrict__ Vin,
    float* __restrict__ pK, float* __restrict__ pV) {
  const int perT = (BATCH * DM) * 32;    // 663552 groups per tensor
  for (int t0 = blockIdx.x * 256 + threadIdx.x; t0 < POOL_GROUPS;
       t0 += gridDim.x * 256) {
    int t = t0;
    const float* src;
    float* dst;
    if (t < perT) {
      src = Kin; dst = pK;
    } else {
      src = Vin; dst = pV; t -= perT;
    }
    int row = t >> 5, g = t & 31;
    const float* p = src + (size_t)row * L + g * 36;

    float4 a0 = *(const float4*)(p + 0);
    float4 a1 = *(const float4*)(p + 4);
    float4 a2 = *(const float4*)(p + 8);
    float4 a3 = *(const float4*)(p + 12);
    float4 a4 = *(const float4*)(p + 16);
    float4 a5 = *(const float4*)(p + 20);
    float4 a6 = *(const float4*)(p + 24);
    float4 a7 = *(const float4*)(p + 28);
    float4 h = make_float4(-INFINITY, -INFINITY, -INFINITY, -INFINITY);
    if (g > 0) h = *(const float4*)(p - 4);

    float w0 = fmaxf(fmaxf(fmaxf(h.x, h.y), fmaxf(h.z, h.w)),
                     fmaxf(fmaxf(fmaxf(a0.x, a0.y), fmaxf(a0.z, a0.w)), a1.x));
    float w1 = fmaxf(fmaxf(fmaxf(a1.y, a1.z), fmaxf(a1.w, a2.x)),
                     fmaxf(fmaxf(fmaxf(a2.y, a2.z), fmaxf(a2.w, a3.x)), a3.y));
    float w2 = fmaxf(fmaxf(fmaxf(a3.z, a3.w), fmaxf(a4.x, a4.y)),
                     fmaxf(fmaxf(fmaxf(a4.z, a4.w), fmaxf(a5.x, a5.y)), a5.z));
    float w3 = fmaxf(fmaxf(fmaxf(a5.w, a6.x), fmaxf(a6.y, a6.z)),
                     fmaxf(fmaxf(fmaxf(a6.w, a7.x), fmaxf(a7.y, a7.z)), a7.w));

    *(float4*)(dst + (size_t)row * LK + g * 4) = make_float4(w0, w1, w2, w3);
  }
}

// ---------------------------------------------------------------------------
// K2: clustering head (identity-gather form).
// ---------------------------------------------------------------------------
__global__ __launch_bounds__(256) void cluster_kernel(
    const float* __restrict__ pK,
    const float* __restrict__ Wp,  const float* __restrict__ bp,
    const float* __restrict__ Wck, const float* __restrict__ bck,
    const float* __restrict__ Wcq, const float* __restrict__ bcq,
    float* __restrict__ cq_out, float* __restrict__ ck_out,
    float* __restrict__ loss_acc) {
  int bb = blockIdx.x / 9;
  int s  = blockIdx.x % 9;
  int tid = threadIdx.x;

  __shared__ float sK[256 * 33];
  __shared__ float sWp[1728];
  __shared__ float red[256];

  for (int i = tid; i < 1728; i += 256) sWp[i] = Wp[i];

  float a0 = 0.f, a1 = 0.f, a2 = 0.f;
  int umin = (bb >= 18) ? 0 : (18 - bb);

  for (int u = umin; u < 18; ++u) {
    int b2 = bb + u - 17;
    __syncthreads();
    const float4* src = (const float4*)(pK + (size_t)b2 * POOL_PER_B + s * 8192);
#pragma unroll
    for (int k = 0; k < 8; ++k) {
      int i = tid + k * 256;
      float4 v = src[i];
      int base = i * 4;
      float* dst = &sK[(base >> 5) * 33 + (base & 31)];
      dst[0] = v.x; dst[1] = v.y; dst[2] = v.z; dst[3] = v.w;
    }
    __syncthreads();
    const float* wrow = &sWp[u * 3];
    const float* krow = &sK[tid * 33];
#pragma unroll
    for (int g = 0; g < 32; ++g) {
      float v = krow[g];
      a0 = fmaf(v, wrow[g * 54 + 0], a0);
      a1 = fmaf(v, wrow[g * 54 + 1], a1);
      a2 = fmaf(v, wrow[g * 54 + 2], a2);
    }
  }

  float p0 = fmaxf(a0 + bp[0], 0.f);
  float p1 = fmaxf(a1 + bp[1], 0.f);
  float p2 = fmaxf(a2 + bp[2], 0.f);

  float k0 = p0 * Wck[0] + p1 * Wck[3] + p2 * Wck[6] + bck[0];
  float k1 = p0 * Wck[1] + p1 * Wck[4] + p2 * Wck[7] + bck[1];
  float k2 = p0 * Wck[2] + p1 * Wck[5] + p2 * Wck[8] + bck[2];
  float mk = fmaxf(k0, fmaxf(k1, k2));
  float e0 = __expf(k0 - mk), e1 = __expf(k1 - mk), e2 = __expf(k2 - mk);
  float inv = 1.f / (e0 + e1 + e2);
  float ck0 = e0 * inv, ck1 = e1 * inv, ck2 = e2 * inv;

  float q0 = p0 * Wcq[0] + p1 * Wcq[3] + p2 * Wcq[6] + bcq[0];
  float q1 = p0 * Wcq[1] + p1 * Wcq[4] + p2 * Wcq[7] + bcq[1];
  float q2 = p0 * Wcq[2] + p1 * Wcq[5] + p2 * Wcq[8] + bcq[2];
  float mq = fmaxf(q0, fmaxf(q1, q2));
  float f0 = __expf(q0 - mq), f1 = __expf(q1 - mq), f2 = __expf(q2 - mq);
  float invq = 1.f / (f0 + f1 + f2);
  float cq0 = f0 * invq, cq1 = f1 * invq, cq2 = f2 * invq;

  size_t t = (size_t)bb * 2304 + s * 256 + tid;
  ck_out[t * 3 + 0] = ck0;
  ck_out[t * 3 + 1] = ck1;
  ck_out[t * 3 + 2] = ck2;
  cq_out[t * 3 + 0] = cq0;
  cq_out[t * 3 + 1] = cq1;
  cq_out[t * 3 + 2] = cq2;

  float mean = (cq0 + cq1 + cq2) * (1.f / 3.f);
  float d0 = cq0 - mean, d1 = cq1 - mean, d2 = cq2 - mean;
  float var = (d0 * d0 + d1 * d1 + d2 * d2) * 0.5f;
  float sd  = sqrtf(var);
  float sig = log1pf(__expf(sd));
  float ls  = logf(sig);

  __syncthreads();
  red[tid] = ls;
  __syncthreads();
  for (int r = 128; r > 0; r >>= 1) {
    if (tid < r) red[tid] += red[tid + r];
    __syncthreads();
  }
  if (tid == 0) atomicAdd(loss_acc, red[0]);
}

// ---------------------------------------------------------------------------
// K3: per (bb, lk2): causal 18x18 attention + Wb head + disjoint maxpool.
// ---------------------------------------------------------------------------
__global__ __launch_bounds__(256) void center_kernel(
    const float* __restrict__ cq, const float* __restrict__ ck,
    const float* __restrict__ Wb, const float* __restrict__ bbias,
    float* __restrict__ ccpool) {
  int blk = blockIdx.x;
  int bb  = blk / LK;
  int lk2 = blk % LK;
  int tid = threadIdx.x;

  __shared__ float scq[54], sck[54], sq2[54];
  __shared__ float sWb[3 * 576];
  __shared__ float sbb[576];

  const float* cqb = cq + ((size_t)bb * (LK * B2) + (size_t)lk2 * B2) * 3;
  const float* ckb = ck + ((size_t)bb * (LK * B2) + (size_t)lk2 * B2) * 3;
  if (tid < 54) { scq[tid] = cqb[tid]; sck[tid] = ckb[tid]; }
  for (int i = tid; i < 1728; i += 256) sWb[i] = Wb[i];
  for (int i = tid; i < 576; i += 256) sbb[i] = bbias[i];
  __syncthreads();

  if (tid < B2) {
    int p = tid;
    float s[B2];
    float g0 = scq[p * 3 + 0], g1 = scq[p * 3 + 1], g2 = scq[p * 3 + 2];
    float mx = -INFINITY;
#pragma unroll
    for (int u = 0; u < B2; ++u) {
      float sv = (g0 * sck[u * 3] + g1 * sck[u * 3 + 1] + g2 * sck[u * 3 + 2]) *
                 (1.f / 3.f);
      if (u > p) sv = -1e9f;
      s[u] = sv;
      mx = fmaxf(mx, sv);
    }
    float sum = 0.f;
#pragma unroll
    for (int u = 0; u < B2; ++u) { s[u] = __expf(s[u] - mx); sum += s[u]; }
    float inv = 1.f / sum;
    float o0 = 0.f, o1 = 0.f, o2 = 0.f;
#pragma unroll
    for (int u = 0; u < B2; ++u) {
      float a = s[u] * inv;
      o0 = fmaf(a, scq[u * 3 + 0], o0);
      o1 = fmaf(a, scq[u * 3 + 1], o1);
      o2 = fmaf(a, scq[u * 3 + 2], o2);
    }
    sq2[p * 3 + 0] = o0; sq2[p * 3 + 1] = o1; sq2[p * 3 + 2] = o2;
  }
  __syncthreads();

  float* outb = ccpool + (size_t)bb * CCPOOL_PER_B + (size_t)lk2 * (B2 * 64);
  for (int i = tid; i < B2 * 64; i += 256) {
    int p = i >> 6;
    int w = i & 63;
    float g0 = sq2[p * 3 + 0], g1 = sq2[p * 3 + 1], g2 = sq2[p * 3 + 2];
    int t0 = w * 9 - 4;
    int lo = t0 < 0 ? 0 : t0;
    int hi = t0 + 8; if (hi > 575) hi = 575;
    float mxv = -INFINITY;
    for (int tt = lo; tt <= hi; ++tt) {
      float cv = g0 * sWb[tt] + g1 * sWb[576 + tt] + g2 * sWb[1152 + tt] + sbb[tt];
      cv = fmaxf(cv, 0.f);
      mxv = fmaxf(mxv, cv);
    }
    outb[i] = mxv;
  }
}

// ---------------------------------------------------------------------------
// K4a: prep MFMA operand fragments — bf16 (hi only) of Csum and Vp.
// Per-bh contiguous: Cfrag 1536 uint4, Vfrag 1280 uint4.
// ---------------------------------------------------------------------------
#define CFRAG_T (NBH*8*3*64)   // 442368
#define VFRAG_T (NBH*5*4*64)   // 368640
__global__ __launch_bounds__(256) void prep_kernel(
    const float* __restrict__ ccpool, const float* __restrict__ pV,
    uint4* __restrict__ Cfrag, uint4* __restrict__ Vfrag) {
  int t = blockIdx.x * 256 + threadIdx.x;   // 811008 exactly
  unsigned short hi[8];
  if (t < CFRAG_T) {
    int lane = t & 63;
    int rest = t >> 6;
    int ks = rest % 3;
    int mtb = rest / 3;
    int mt = mtb & 7;
    int bh = mtb >> 3;
    int bb = bh >> 3, hh = bh & 7;
    int key = mt * 16 + (lane & 15);
    int d0 = ks * 32 + (lane >> 4) * 8;
    const float* cp = ccpool + (size_t)bb * CCPOOL_PER_B + hh * 18432 + key * 72;
#pragma unroll
    for (int j = 0; j < 8; ++j) {
      int d = d0 + j;
      float v = (d < 72) ? (cp[d] + cp[9216 + d]) : 0.f;
      hi[j] = bf16_rne(v);
    }
    uint4 h4;
    h4.x = hi[0] | (hi[1] << 16); h4.y = hi[2] | (hi[3] << 16);
    h4.z = hi[4] | (hi[5] << 16); h4.w = hi[6] | (hi[7] << 16);
    Cfrag[t] = h4;
  } else {
    int t2 = t - CFRAG_T;
    int lane = t2 & 63;
    int rest = t2 >> 6;
    int ks = rest & 3;
    int ntb = rest >> 2;
    int nt = ntb % 5;
    int bh = ntb / 5;
    int d = nt * 16 + (lane & 15);
    int k0 = ks * 32 + (lane >> 4) * 8;
    const float* vp = pV + (size_t)bh * (LK * DK);
#pragma unroll
    for (int j = 0; j < 8; ++j) {
      int k = k0 + j;
      float v = (d < 72) ? vp[k * 72 + d] : 0.f;
      hi[j] = bf16_rne(v);
    }
    uint4 h4;
    h4.x = hi[0] | (hi[1] << 16); h4.y = hi[2] | (hi[3] << 16);
    h4.z = hi[4] | (hi[5] << 16); h4.w = hi[6] | (hi[7] << 16);
    Vfrag[t2] = h4;
  }
}

// ---------------------------------------------------------------------------
// K4b: MFMA attention. 2 subtiles/wave; C fragments staged in LDS (24 KB ->
// 6 blocks/CU LDS-cap, up from 3 at 44 KB); V fragments read direct from
// global (7.5 MB, L2-resident). bf16 Q.
// ---------------------------------------------------------------------------
__global__ __launch_bounds__(256) void attn2_kernel(
    const float* __restrict__ Q, const uint4* __restrict__ Cfrag,
    const uint4* __restrict__ Vfrag, float* __restrict__ out) {
  __shared__ __align__(16) uint4 sFrag[1536];   // 24 KB: C only

  int bh = blockIdx.x / 9, qt = blockIdx.x % 9;
  int tid = threadIdx.x;
  int wid = tid >> 6, lane = tid & 63;
  int lq = lane & 15, lg = lane >> 4;
  int qbase = qt * 128 + wid * 32;

  // ---- stage C fragments once per block (coalesced, 6 iters/thread) ----
  const uint4* gC = Cfrag + (size_t)bh * 1536;
  const uint4* gV = Vfrag + (size_t)bh * 1280;
#pragma unroll
  for (int k = 0; k < 6; ++k) sFrag[tid + k * 256] = gC[tid + k * 256];
  __syncthreads();

  f32x4 sacc[2][8];
#pragma unroll
  for (int s = 0; s < 2; ++s)
#pragma unroll
    for (int mt = 0; mt < 8; ++mt) sacc[s][mt] = (f32x4){0.f, 0.f, 0.f, 0.f};

  // ---- S^T = C * Q^T (bf16 Q) ----
#pragma unroll
  for (int ks = 0; ks < 3; ++ks) {
    short8 qh[2];
#pragma unroll
    for (int s = 0; s < 2; ++s) {
      int q = qbase + s * 16 + lq;
      const float* qrow = Q + ((size_t)bh * L + q) * DK;
      int d0 = ks * 32 + lg * 8;
      float x[8];
      if (ks < 2) {
        float4 a = *(const float4*)(qrow + d0);
        float4 b = *(const float4*)(qrow + d0 + 4);
        x[0] = a.x; x[1] = a.y; x[2] = a.z; x[3] = a.w;
        x[4] = b.x; x[5] = b.y; x[6] = b.z; x[7] = b.w;
      } else {
        if (lg == 0) {
          float4 a = *(const float4*)(qrow + 64);
          float4 b = *(const float4*)(qrow + 68);
          x[0] = a.x; x[1] = a.y; x[2] = a.z; x[3] = a.w;
          x[4] = b.x; x[5] = b.y; x[6] = b.z; x[7] = b.w;
        } else {
#pragma unroll
          for (int j = 0; j < 8; ++j) x[j] = 0.f;
        }
      }
#pragma unroll
      for (int j = 0; j < 8; ++j) qh[s][j] = (short)bf16_rne(x[j]);
    }
#pragma unroll
    for (int mt = 0; mt < 8; ++mt) {
      short8 chi = *(const short8*)&sFrag[(mt * 3 + ks) * 64 + lane];
#pragma unroll
      for (int s = 0; s < 2; ++s)
        sacc[s][mt] = __builtin_amdgcn_mfma_f32_16x16x32_bf16(chi, qh[s], sacc[s][mt], 0, 0, 0);
    }
  }

  // ---- softmax over keys (per q-col), normalized P packed as bf16 pairs ----
  unsigned pw[2][8][2];
#pragma unroll
  for (int s = 0; s < 2; ++s) {
    float mx = -INFINITY;
#pragma unroll
    for (int mt = 0; mt < 8; ++mt)
#pragma unroll
      for (int r = 0; r < 4; ++r) mx = fmaxf(mx, sacc[s][mt][r]);
    mx = fmaxf(mx, __shfl_xor(mx, 16));
    mx = fmaxf(mx, __shfl_xor(mx, 32));
    float sum = 0.f;
#pragma unroll
    for (int mt = 0; mt < 8; ++mt)
#pragma unroll
      for (int r = 0; r < 4; ++r) {
        float p = __expf(sacc[s][mt][r] - mx);
        sacc[s][mt][r] = p;
        sum += p;
      }
    sum += __shfl_xor(sum, 16);
    sum += __shfl_xor(sum, 32);
    float inv = 1.f / sum;
#pragma unroll
    for (int mt = 0; mt < 8; ++mt) {
      pw[s][mt][0] = pack2(sacc[s][mt][0] * inv, sacc[s][mt][1] * inv);
      pw[s][mt][1] = pack2(sacc[s][mt][2] * inv, sacc[s][mt][3] * inv);
    }
  }

  // ---- O = P * V via shfl transpose; V direct from global (L2) ----
  f32x4 oacc[2][5];
#pragma unroll
  for (int s = 0; s < 2; ++s)
#pragma unroll
    for (int nt = 0; nt < 5; ++nt) oacc[s][nt] = (f32x4){0.f, 0.f, 0.f, 0.f};

  int baseA = lq + 32 * (lg & 1);
  int baseB = baseA + 16;
  bool hiGrp = (lg & 2) != 0;

#pragma unroll
  for (int ks = 0; ks < 4; ++ks) {
    short8 pa[2];
#pragma unroll
    for (int s = 0; s < 2; ++s) {
      unsigned a0 = pw[s][2 * ks][0],     a1 = pw[s][2 * ks][1];
      unsigned b0 = pw[s][2 * ks + 1][0], b1 = pw[s][2 * ks + 1][1];
      unsigned r00 = __shfl(a0, baseA, 64), r10 = __shfl(b0, baseA, 64);
      unsigned r01 = __shfl(a1, baseA, 64), r11 = __shfl(b1, baseA, 64);
      unsigned r02 = __shfl(a0, baseB, 64), r12 = __shfl(b0, baseB, 64);
      unsigned r03 = __shfl(a1, baseB, 64), r13 = __shfl(b1, baseB, 64);
      uint4 u;
      u.x = hiGrp ? r10 : r00;
      u.y = hiGrp ? r11 : r01;
      u.z = hiGrp ? r12 : r02;
      u.w = hiGrp ? r13 : r03;
      pa[s] = *(short8*)&u;
    }
#pragma unroll
    for (int nt = 0; nt < 5; ++nt) {
      short8 vhi = *(const short8*)(gV + (nt * 4 + ks) * 64 + lane);
#pragma unroll
      for (int s = 0; s < 2; ++s)
        oacc[s][nt] = __builtin_amdgcn_mfma_f32_16x16x32_bf16(pa[s], vhi, oacc[s][nt], 0, 0, 0);
    }
  }

  // ---- store: D layout col=lane&15 (d), row=(lane>>4)*4+r (q) ----
#pragma unroll
  for (int s = 0; s < 2; ++s) {
#pragma unroll
    for (int nt = 0; nt < 5; ++nt) {
      int d = nt * 16 + lq;
      if (d < 72) {
        float* orow = out + ((size_t)bh * L + qbase + s * 16 + lg * 4) * DK + d;
#pragma unroll
        for (int r = 0; r < 4; ++r) orow[(size_t)r * DK] = oacc[s][nt][r];
      }
    }
  }
}

// ---------------------------------------------------------------------------
// K5: finalize loss (mu == xk == 1/3 exactly; ce is a constant).
// ---------------------------------------------------------------------------
__global__ void finalize_kernel(const float* __restrict__ loss_acc,
                                float* __restrict__ out_loss) {
  *out_loss = loss_acc[0] * (1.f / 82944.f) + 207.93889646f;
}

extern "C" void kernel_launch(void* const* d_in, const int* in_sizes, int n_in,
                              void* d_out, int out_size, void* d_ws, size_t ws_size,
                              hipStream_t stream) {
  const float* Q    = (const float*)d_in[0];
  const float* Kin  = (const float*)d_in[1];
  const float* Vin  = (const float*)d_in[2];
  const float* Wp   = (const float*)d_in[3];
  const float* bp   = (const float*)d_in[4];
  const float* Wck  = (const float*)d_in[5];
  const float* bck  = (const float*)d_in[6];
  const float* Wcq  = (const float*)d_in[7];
  const float* bcq  = (const float*)d_in[8];
  const float* Wb   = (const float*)d_in[9];
  const float* bbv  = (const float*)d_in[10];
  float* out = (float*)d_out;

  float* ws = (float*)d_ws;
  float* pK       = ws;
  float* pV       = pK + POOL_TOTAL;
  float* cq       = pV + POOL_TOTAL;
  float* ck       = cq + (size_t)CLUS_TOTAL * 3;
  float* ccpool   = ck + (size_t)CLUS_TOTAL * 3;
  float* cfrag_f  = ccpool + (size_t)BATCH * CCPOOL_PER_B;
  uint4* Cfrag    = (uint4*)cfrag_f;
  uint4* Vfrag    = Cfrag + (size_t)CFRAG_T;
  float* loss_acc = (float*)(Vfrag + (size_t)VFRAG_T);

  hipMemsetAsync(loss_acc, 0, sizeof(float), stream);

  pool_kernel<<<2048, 256, 0, stream>>>(Kin, Vin, pK, pV);
  cluster_kernel<<<BATCH * 9, 256, 0, stream>>>(
      pK, Wp, bp, Wck, bck, Wcq, bcq, cq, ck, loss_acc);
  center_kernel<<<BATCH * LK, 256, 0, stream>>>(cq, ck, Wb, bbv, ccpool);
  prep_kernel<<<(CFRAG_T + VFRAG_T) / 256, 256, 0, stream>>>(ccpool, pV, Cfrag, Vfrag);
  attn2_kernel<<<NBH * 9, 256, 0, stream>>>(Q, Cfrag, Vfrag, out);
  finalize_kernel<<<1, 1, 0, stream>>>(loss_acc, out + CTX_ELEMS);
}

// Round 10
// 195.776 us; speedup vs baseline: 1.0026x; 1.0026x over previous
//
#include <hip/hip_runtime.h>
#include <math.h>

#define BATCH 36
#define H 8
#define L 1152
#define DK 72
#define DM 576
#define LK 128
#define B2 18
#define NC 3

// derived
#define POOL_PER_B (DM*LK)            // 73728
#define POOL_TOTAL (BATCH*POOL_PER_B) // 2654208
#define CLUS_TOTAL (BATCH*LK*B2)      // 82944
#define CCPOOL_PER_B (LK*B2*64)       // 147456
#define CTX_ELEMS (BATCH*H*L*DK)      // 23887872
#define NBH (BATCH*H)                 // 288

typedef __attribute__((ext_vector_type(8))) short short8;
typedef __attribute__((ext_vector_type(4))) float f32x4;

// round-to-nearest-even fp32 -> bf16 bits
__device__ __forceinline__ unsigned short bf16_rne(float x) {
  unsigned u = __float_as_uint(x);
  unsigned r = u + 0x7FFFu + ((u >> 16) & 1u);
  return (unsigned short)(r >> 16);
}
__device__ __forceinline__ unsigned pack2(float a, float b) {
  return (unsigned)bf16_rne(a) | ((unsigned)bf16_rne(b) << 16);
}

// ---------------------------------------------------------------------------
// K1: MaxPool1d(kernel=9, stride=9, pad=4) — coalesced LDS staging at HIGH
// occupancy: PROWS=4 -> 18 KB LDS -> 8 blocks/CU (vs R4's 36KB/4 blocks).
// Staging is m13-copy-style coalesced float4; compute reads 9 consecutive
// LDS floats per window (odd lane stride -> conflict-free); output coalesced.
// This is the decisive test of the ~3 TB/s service-wall hypothesis.
// ---------------------------------------------------------------------------
#define PROWS 4
__global__ __launch_bounds__(256) void pool_kernel(
    const float* __restrict__ Kin, const float* __restrict__ Vin,
    float* __restrict__ pK, float* __restrict__ pV) {
  __shared__ float sIn[PROWS * L];    // 18 KB

  int bid = blockIdx.x;
  const int half = (BATCH * DM) / PROWS;   // 5184
  const float* src;
  float* dst;
  if (bid < half) {
    src = Kin + (size_t)bid * (PROWS * L);
    dst = pK + (size_t)bid * (PROWS * LK);
  } else {
    src = Vin + (size_t)(bid - half) * (PROWS * L);
    dst = pV + (size_t)(bid - half) * (PROWS * LK);
  }
  int tid = threadIdx.x;

  const float4* s4 = (const float4*)src;
  float4* l4 = (float4*)sIn;
#pragma unroll
  for (int k = 0; k < 4; ++k)              // 1024 of 1152 float4
    l4[tid + k * 256] = s4[tid + k * 256];
  if (tid < 128) l4[tid + 1024] = s4[tid + 1024];
  __syncthreads();

#pragma unroll
  for (int k = 0; k < 2; ++k) {            // 512 outputs, 2/thread
    int o = tid + k * 256;
    int row = o >> 7, w = o & 127;
    int base = row * L;
    int s0 = w * 9 - 4;                    // >= -4; max index w*9+4 <= 1147
    float m = -INFINITY;
#pragma unroll
    for (int j = 0; j < 9; ++j) {
      int t = s0 + j;
      t = t < 0 ? 0 : t;
      m = fmaxf(m, sIn[base + t]);
    }
    dst[o] = m;
  }
}

// ---------------------------------------------------------------------------
// K2: clustering head (identity-gather form).
// ---------------------------------------------------------------------------
__global__ __launch_bounds__(256) void cluster_kernel(
    const float* __restrict__ pK,
    const float* __restrict__ Wp,  const float* __restrict__ bp,
    const float* __restrict__ Wck, const float* __restrict__ bck,
    const float* __restrict__ Wcq, const float* __restrict__ bcq,
    float* __restrict__ cq_out, float* __restrict__ ck_out,
    float* __restrict__ loss_acc) {
  int bb = blockIdx.x / 9;
  int s  = blockIdx.x % 9;
  int tid = threadIdx.x;

  __shared__ float sK[256 * 33];
  __shared__ float sWp[1728];
  __shared__ float red[256];

  for (int i = tid; i < 1728; i += 256) sWp[i] = Wp[i];

  float a0 = 0.f, a1 = 0.f, a2 = 0.f;
  int umin = (bb >= 18) ? 0 : (18 - bb);

  for (int u = umin; u < 18; ++u) {
    int b2 = bb + u - 17;
    __syncthreads();
    const float4* src = (const float4*)(pK + (size_t)b2 * POOL_PER_B + s * 8192);
#pragma unroll
    for (int k = 0; k < 8; ++k) {
      int i = tid + k * 256;
      float4 v = src[i];
      int base = i * 4;
      float* dst = &sK[(base >> 5) * 33 + (base & 31)];
      dst[0] = v.x; dst[1] = v.y; dst[2] = v.z; dst[3] = v.w;
    }
    __syncthreads();
    const float* wrow = &sWp[u * 3];
    const float* krow = &sK[tid * 33];
#pragma unroll
    for (int g = 0; g < 32; ++g) {
      float v = krow[g];
      a0 = fmaf(v, wrow[g * 54 + 0], a0);
      a1 = fmaf(v, wrow[g * 54 + 1], a1);
      a2 = fmaf(v, wrow[g * 54 + 2], a2);
    }
  }

  float p0 = fmaxf(a0 + bp[0], 0.f);
  float p1 = fmaxf(a1 + bp[1], 0.f);
  float p2 = fmaxf(a2 + bp[2], 0.f);

  float k0 = p0 * Wck[0] + p1 * Wck[3] + p2 * Wck[6] + bck[0];
  float k1 = p0 * Wck[1] + p1 * Wck[4] + p2 * Wck[7] + bck[1];
  float k2 = p0 * Wck[2] + p1 * Wck[5] + p2 * Wck[8] + bck[2];
  float mk = fmaxf(k0, fmaxf(k1, k2));
  float e0 = __expf(k0 - mk), e1 = __expf(k1 - mk), e2 = __expf(k2 - mk);
  float inv = 1.f / (e0 + e1 + e2);
  float ck0 = e0 * inv, ck1 = e1 * inv, ck2 = e2 * inv;

  float q0 = p0 * Wcq[0] + p1 * Wcq[3] + p2 * Wcq[6] + bcq[0];
  float q1 = p0 * Wcq[1] + p1 * Wcq[4] + p2 * Wcq[7] + bcq[1];
  float q2 = p0 * Wcq[2] + p1 * Wcq[5] + p2 * Wcq[8] + bcq[2];
  float mq = fmaxf(q0, fmaxf(q1, q2));
  float f0 = __expf(q0 - mq), f1 = __expf(q1 - mq), f2 = __expf(q2 - mq);
  float invq = 1.f / (f0 + f1 + f2);
  float cq0 = f0 * invq, cq1 = f1 * invq, cq2 = f2 * invq;

  size_t t = (size_t)bb * 2304 + s * 256 + tid;
  ck_out[t * 3 + 0] = ck0;
  ck_out[t * 3 + 1] = ck1;
  ck_out[t * 3 + 2] = ck2;
  cq_out[t * 3 + 0] = cq0;
  cq_out[t * 3 + 1] = cq1;
  cq_out[t * 3 + 2] = cq2;

  float mean = (cq0 + cq1 + cq2) * (1.f / 3.f);
  float d0 = cq0 - mean, d1 = cq1 - mean, d2 = cq2 - mean;
  float var = (d0 * d0 + d1 * d1 + d2 * d2) * 0.5f;
  float sd  = sqrtf(var);
  float sig = log1pf(__expf(sd));
  float ls  = logf(sig);

  __syncthreads();
  red[tid] = ls;
  __syncthreads();
  for (int r = 128; r > 0; r >>= 1) {
    if (tid < r) red[tid] += red[tid + r];
    __syncthreads();
  }
  if (tid == 0) atomicAdd(loss_acc, red[0]);
}

// ---------------------------------------------------------------------------
// K3: per (bb, lk2): causal 18x18 attention + Wb head + disjoint maxpool.
// ---------------------------------------------------------------------------
__global__ __launch_bounds__(256) void center_kernel(
    const float* __restrict__ cq, const float* __restrict__ ck,
    const float* __restrict__ Wb, const float* __restrict__ bbias,
    float* __restrict__ ccpool) {
  int blk = blockIdx.x;
  int bb  = blk / LK;
  int lk2 = blk % LK;
  int tid = threadIdx.x;

  __shared__ float scq[54], sck[54], sq2[54];
  __shared__ float sWb[3 * 576];
  __shared__ float sbb[576];

  const float* cqb = cq + ((size_t)bb * (LK * B2) + (size_t)lk2 * B2) * 3;
  const float* ckb = ck + ((size_t)bb * (LK * B2) + (size_t)lk2 * B2) * 3;
  if (tid < 54) { scq[tid] = cqb[tid]; sck[tid] = ckb[tid]; }
  for (int i = tid; i < 1728; i += 256) sWb[i] = Wb[i];
  for (int i = tid; i < 576; i += 256) sbb[i] = bbias[i];
  __syncthreads();

  if (tid < B2) {
    int p = tid;
    float s[B2];
    float g0 = scq[p * 3 + 0], g1 = scq[p * 3 + 1], g2 = scq[p * 3 + 2];
    float mx = -INFINITY;
#pragma unroll
    for (int u = 0; u < B2; ++u) {
      float sv = (g0 * sck[u * 3] + g1 * sck[u * 3 + 1] + g2 * sck[u * 3 + 2]) *
                 (1.f / 3.f);
      if (u > p) sv = -1e9f;
      s[u] = sv;
      mx = fmaxf(mx, sv);
    }
    float sum = 0.f;
#pragma unroll
    for (int u = 0; u < B2; ++u) { s[u] = __expf(s[u] - mx); sum += s[u]; }
    float inv = 1.f / sum;
    float o0 = 0.f, o1 = 0.f, o2 = 0.f;
#pragma unroll
    for (int u = 0; u < B2; ++u) {
      float a = s[u] * inv;
      o0 = fmaf(a, scq[u * 3 + 0], o0);
      o1 = fmaf(a, scq[u * 3 + 1], o1);
      o2 = fmaf(a, scq[u * 3 + 2], o2);
    }
    sq2[p * 3 + 0] = o0; sq2[p * 3 + 1] = o1; sq2[p * 3 + 2] = o2;
  }
  __syncthreads();

  float* outb = ccpool + (size_t)bb * CCPOOL_PER_B + (size_t)lk2 * (B2 * 64);
  for (int i = tid; i < B2 * 64; i += 256) {
    int p = i >> 6;
    int w = i & 63;
    float g0 = sq2[p * 3 + 0], g1 = sq2[p * 3 + 1], g2 = sq2[p * 3 + 2];
    int t0 = w * 9 - 4;
    int lo = t0 < 0 ? 0 : t0;
    int hi = t0 + 8; if (hi > 575) hi = 575;
    float mxv = -INFINITY;
    for (int tt = lo; tt <= hi; ++tt) {
      float cv = g0 * sWb[tt] + g1 * sWb[576 + tt] + g2 * sWb[1152 + tt] + sbb[tt];
      cv = fmaxf(cv, 0.f);
      mxv = fmaxf(mxv, cv);
    }
    outb[i] = mxv;
  }
}

// ---------------------------------------------------------------------------
// K4a: prep MFMA operand fragments — bf16 (hi only) of Csum and Vp.
// Per-bh contiguous: Cfrag 1536 uint4, Vfrag 1280 uint4.
// ---------------------------------------------------------------------------
#define CFRAG_T (NBH*8*3*64)   // 442368
#define VFRAG_T (NBH*5*4*64)   // 368640
__global__ __launch_bounds__(256) void prep_kernel(
    const float* __restrict__ ccpool, const float* __restrict__ pV,
    uint4* __restrict__ Cfrag, uint4* __restrict__ Vfrag) {
  int t = blockIdx.x * 256 + threadIdx.x;   // 811008 exactly
  unsigned short hi[8];
  if (t < CFRAG_T) {
    int lane = t & 63;
    int rest = t >> 6;
    int ks = rest % 3;
    int mtb = rest / 3;
    int mt = mtb & 7;
    int bh = mtb >> 3;
    int bb = bh >> 3, hh = bh & 7;
    int key = mt * 16 + (lane & 15);
    int d0 = ks * 32 + (lane >> 4) * 8;
    const float* cp = ccpool + (size_t)bb * CCPOOL_PER_B + hh * 18432 + key * 72;
#pragma unroll
    for (int j = 0; j < 8; ++j) {
      int d = d0 + j;
      float v = (d < 72) ? (cp[d] + cp[9216 + d]) : 0.f;
      hi[j] = bf16_rne(v);
    }
    uint4 h4;
    h4.x = hi[0] | (hi[1] << 16); h4.y = hi[2] | (hi[3] << 16);
    h4.z = hi[4] | (hi[5] << 16); h4.w = hi[6] | (hi[7] << 16);
    Cfrag[t] = h4;
  } else {
    int t2 = t - CFRAG_T;
    int lane = t2 & 63;
    int rest = t2 >> 6;
    int ks = rest & 3;
    int ntb = rest >> 2;
    int nt = ntb % 5;
    int bh = ntb / 5;
    int d = nt * 16 + (lane & 15);
    int k0 = ks * 32 + (lane >> 4) * 8;
    const float* vp = pV + (size_t)bh * (LK * DK);
#pragma unroll
    for (int j = 0; j < 8; ++j) {
      int k = k0 + j;
      float v = (d < 72) ? vp[k * 72 + d] : 0.f;
      hi[j] = bf16_rne(v);
    }
    uint4 h4;
    h4.x = hi[0] | (hi[1] << 16); h4.y = hi[2] | (hi[3] << 16);
    h4.z = hi[4] | (hi[5] << 16); h4.w = hi[6] | (hi[7] << 16);
    Vfrag[t2] = h4;
  }
}

// ---------------------------------------------------------------------------
// K4b: MFMA attention (R8-proven config): 2 subtiles/wave, full 44 KB block-
// shared LDS staging of C+V fragments, bf16 Q, shfl-transposed P.
// ---------------------------------------------------------------------------
__global__ __launch_bounds__(256) void attn2_kernel(
    const float* __restrict__ Q, const uint4* __restrict__ Cfrag,
    const uint4* __restrict__ Vfrag, float* __restrict__ out) {
  __shared__ __align__(16) uint4 sFrag[2816];   // 44 KB: C [0,1536) V [1536,2816)

  int bh = blockIdx.x / 9, qt = blockIdx.x % 9;
  int tid = threadIdx.x;
  int wid = tid >> 6, lane = tid & 63;
  int lq = lane & 15, lg = lane >> 4;
  int qbase = qt * 128 + wid * 32;

  const uint4* gC = Cfrag + (size_t)bh * 1536;
  const uint4* gV = Vfrag + (size_t)bh * 1280;
#pragma unroll
  for (int k = 0; k < 6; ++k) sFrag[tid + k * 256] = gC[tid + k * 256];
#pragma unroll
  for (int k = 0; k < 5; ++k) sFrag[1536 + tid + k * 256] = gV[tid + k * 256];
  __syncthreads();

  f32x4 sacc[2][8];
#pragma unroll
  for (int s = 0; s < 2; ++s)
#pragma unroll
    for (int mt = 0; mt < 8; ++mt) sacc[s][mt] = (f32x4){0.f, 0.f, 0.f, 0.f};

  // ---- S^T = C * Q^T (bf16 Q) ----
#pragma unroll
  for (int ks = 0; ks < 3; ++ks) {
    short8 qh[2];
#pragma unroll
    for (int s = 0; s < 2; ++s) {
      int q = qbase + s * 16 + lq;
      const float* qrow = Q + ((size_t)bh * L + q) * DK;
      int d0 = ks * 32 + lg * 8;
      float x[8];
      if (ks < 2) {
        float4 a = *(const float4*)(qrow + d0);
        float4 b = *(const float4*)(qrow + d0 + 4);
        x[0] = a.x; x[1] = a.y; x[2] = a.z; x[3] = a.w;
        x[4] = b.x; x[5] = b.y; x[6] = b.z; x[7] = b.w;
      } else {
        if (lg == 0) {
          float4 a = *(const float4*)(qrow + 64);
          float4 b = *(const float4*)(qrow + 68);
          x[0] = a.x; x[1] = a.y; x[2] = a.z; x[3] = a.w;
          x[4] = b.x; x[5] = b.y; x[6] = b.z; x[7] = b.w;
        } else {
#pragma unroll
          for (int j = 0; j < 8; ++j) x[j] = 0.f;
        }
      }
#pragma unroll
      for (int j = 0; j < 8; ++j) qh[s][j] = (short)bf16_rne(x[j]);
    }
#pragma unroll
    for (int mt = 0; mt < 8; ++mt) {
      short8 chi = *(const short8*)&sFrag[(mt * 3 + ks) * 64 + lane];
#pragma unroll
      for (int s = 0; s < 2; ++s)
        sacc[s][mt] = __builtin_amdgcn_mfma_f32_16x16x32_bf16(chi, qh[s], sacc[s][mt], 0, 0, 0);
    }
  }

  // ---- softmax over keys (per q-col), normalized P packed as bf16 pairs ----
  unsigned pw[2][8][2];
#pragma unroll
  for (int s = 0; s < 2; ++s) {
    float mx = -INFINITY;
#pragma unroll
    for (int mt = 0; mt < 8; ++mt)
#pragma unroll
      for (int r = 0; r < 4; ++r) mx = fmaxf(mx, sacc[s][mt][r]);
    mx = fmaxf(mx, __shfl_xor(mx, 16));
    mx = fmaxf(mx, __shfl_xor(mx, 32));
    float sum = 0.f;
#pragma unroll
    for (int mt = 0; mt < 8; ++mt)
#pragma unroll
      for (int r = 0; r < 4; ++r) {
        float p = __expf(sacc[s][mt][r] - mx);
        sacc[s][mt][r] = p;
        sum += p;
      }
    sum += __shfl_xor(sum, 16);
    sum += __shfl_xor(sum, 32);
    float inv = 1.f / sum;
#pragma unroll
    for (int mt = 0; mt < 8; ++mt) {
      pw[s][mt][0] = pack2(sacc[s][mt][0] * inv, sacc[s][mt][1] * inv);
      pw[s][mt][1] = pack2(sacc[s][mt][2] * inv, sacc[s][mt][3] * inv);
    }
  }

  // ---- O = P * V via shfl transpose ----
  f32x4 oacc[2][5];
#pragma unroll
  for (int s = 0; s < 2; ++s)
#pragma unroll
    for (int nt = 0; nt < 5; ++nt) oacc[s][nt] = (f32x4){0.f, 0.f, 0.f, 0.f};

  int baseA = lq + 32 * (lg & 1);
  int baseB = baseA + 16;
  bool hiGrp = (lg & 2) != 0;

#pragma unroll
  for (int ks = 0; ks < 4; ++ks) {
    short8 pa[2];
#pragma unroll
    for (int s = 0; s < 2; ++s) {
      unsigned a0 = pw[s][2 * ks][0],     a1 = pw[s][2 * ks][1];
      unsigned b0 = pw[s][2 * ks + 1][0], b1 = pw[s][2 * ks + 1][1];
      unsigned r00 = __shfl(a0, baseA, 64), r10 = __shfl(b0, baseA, 64);
      unsigned r01 = __shfl(a1, baseA, 64), r11 = __shfl(b1, baseA, 64);
      unsigned r02 = __shfl(a0, baseB, 64), r12 = __shfl(b0, baseB, 64);
      unsigned r03 = __shfl(a1, baseB, 64), r13 = __shfl(b1, baseB, 64);
      uint4 u;
      u.x = hiGrp ? r10 : r00;
      u.y = hiGrp ? r11 : r01;
      u.z = hiGrp ? r12 : r02;
      u.w = hiGrp ? r13 : r03;
      pa[s] = *(short8*)&u;
    }
#pragma unroll
    for (int nt = 0; nt < 5; ++nt) {
      short8 vhi = *(const short8*)&sFrag[1536 + (nt * 4 + ks) * 64 + lane];
#pragma unroll
      for (int s = 0; s < 2; ++s)
        oacc[s][nt] = __builtin_amdgcn_mfma_f32_16x16x32_bf16(pa[s], vhi, oacc[s][nt], 0, 0, 0);
    }
  }

  // ---- store: D layout col=lane&15 (d), row=(lane>>4)*4+r (q) ----
#pragma unroll
  for (int s = 0; s < 2; ++s) {
#pragma unroll
    for (int nt = 0; nt < 5; ++nt) {
      int d = nt * 16 + lq;
      if (d < 72) {
        float* orow = out + ((size_t)bh * L + qbase + s * 16 + lg * 4) * DK + d;
#pragma unroll
        for (int r = 0; r < 4; ++r) orow[(size_t)r * DK] = oacc[s][nt][r];
      }
    }
  }
}

// ---------------------------------------------------------------------------
// K5: finalize loss (mu == xk == 1/3 exactly; ce is a constant).
// ---------------------------------------------------------------------------
__global__ void finalize_kernel(const float* __restrict__ loss_acc,
                                float* __restrict__ out_loss) {
  *out_loss = loss_acc[0] * (1.f / 82944.f) + 207.93889646f;
}

extern "C" void kernel_launch(void* const* d_in, const int* in_sizes, int n_in,
                              void* d_out, int out_size, void* d_ws, size_t ws_size,
                              hipStream_t stream) {
  const float* Q    = (const float*)d_in[0];
  const float* Kin  = (const float*)d_in[1];
  const float* Vin  = (const float*)d_in[2];
  const float* Wp   = (const float*)d_in[3];
  const float* bp   = (const float*)d_in[4];
  const float* Wck  = (const float*)d_in[5];
  const float* bck  = (const float*)d_in[6];
  const float* Wcq  = (const float*)d_in[7];
  const float* bcq  = (const float*)d_in[8];
  const float* Wb   = (const float*)d_in[9];
  const float* bbv  = (const float*)d_in[10];
  float* out = (float*)d_out;

  float* ws = (float*)d_ws;
  float* pK       = ws;
  float* pV       = pK + POOL_TOTAL;
  float* cq       = pV + POOL_TOTAL;
  float* ck       = cq + (size_t)CLUS_TOTAL * 3;
  float* ccpool   = ck + (size_t)CLUS_TOTAL * 3;
  float* cfrag_f  = ccpool + (size_t)BATCH * CCPOOL_PER_B;
  uint4* Cfrag    = (uint4*)cfrag_f;
  uint4* Vfrag    = Cfrag + (size_t)CFRAG_T;
  float* loss_acc = (float*)(Vfrag + (size_t)VFRAG_T);

  hipMemsetAsync(loss_acc, 0, sizeof(float), stream);

  pool_kernel<<<2 * (BATCH * DM) / PROWS, 256, 0, stream>>>(Kin, Vin, pK, pV);
  cluster_kernel<<<BATCH * 9, 256, 0, stream>>>(
      pK, Wp, bp, Wck, bck, Wcq, bcq, cq, ck, loss_acc);
  center_kernel<<<BATCH * LK, 256, 0, stream>>>(cq, ck, Wb, bbv, ccpool);
  prep_kernel<<<(CFRAG_T + VFRAG_T) / 256, 256, 0, stream>>>(ccpool, pV, Cfrag, Vfrag);
  attn2_kernel<<<NBH * 9, 256, 0, stream>>>(Q, Cfrag, Vfrag, out);
  finalize_kernel<<<1, 1, 0, stream>>>(loss_acc, out + CTX_ELEMS);
}

// Round 11
// 195.405 us; speedup vs baseline: 1.0045x; 1.0019x over previous
//
#include <hip/hip_runtime.h>
#include <math.h>

#define BATCH 36
#define H 8
#define L 1152
#define DK 72
#define DM 576
#define LK 128
#define B2 18
#define NC 3

// derived
#define POOL_PER_B (DM*LK)            // 73728
#define POOL_TOTAL (BATCH*POOL_PER_B) // 2654208
#define CLUS_TOTAL (BATCH*LK*B2)      // 82944
#define CCPOOL_PER_B (LK*B2*64)       // 147456
#define CTX_ELEMS (BATCH*H*L*DK)      // 23887872
#define NBH (BATCH*H)                 // 288

typedef __attribute__((ext_vector_type(8))) short short8;
typedef __attribute__((ext_vector_type(4))) float f32x4;

// round-to-nearest-even fp32 -> bf16 bits
__device__ __forceinline__ unsigned short bf16_rne(float x) {
  unsigned u = __float_as_uint(x);
  unsigned r = u + 0x7FFFu + ((u >> 16) & 1u);
  return (unsigned short)(r >> 16);
}
__device__ __forceinline__ unsigned pack2(float a, float b) {
  return (unsigned)bf16_rne(a) | ((unsigned)bf16_rne(b) << 16);
}
__device__ __forceinline__ float max9(float x0, float x1, float x2, float x3,
                                      float x4, float x5, float x6, float x7,
                                      float x8) {
  float m0 = fmaxf(fmaxf(x0, x1), x2);   // v_max3 candidates
  float m1 = fmaxf(fmaxf(x3, x4), x5);
  float m2 = fmaxf(fmaxf(x6, x7), x8);
  return fmaxf(fmaxf(m0, m1), m2);
}

// ---------------------------------------------------------------------------
// K1: MaxPool1d(kernel=9, stride=9, pad=4) — MLP-deep register pool.
// One 36-float group (4 windows) per thread: NINE float4 loads held LIVE in
// registers simultaneously (sched_barrier fences the load cluster from the
// max tree so the compiler cannot reuse registers and serialize the loads).
// 9.2 KB in flight per wave covers HBM latency; prior variants (VGPR=12/24)
// had ~2 loads in flight -> the measured ~3 TB/s latency wall.
// ---------------------------------------------------------------------------
__global__ __launch_bounds__(256, 8) void pool_kernel(
    const float* __restrict__ Kin, const float* __restrict__ Vin,
    float* __restrict__ pK, float* __restrict__ pV) {
  int t = blockIdx.x * 256 + threadIdx.x;
  const int perT = (BATCH * DM) * 32;    // 663552 groups per tensor
  const float* src;
  float* dst;
  if (t < perT) {                        // block-uniform (perT % 256 == 0)
    src = Kin; dst = pK;
  } else {
    src = Vin; dst = pV; t -= perT;
  }
  int row = t >> 5, g = t & 31;
  const float* p = src + (size_t)row * L + g * 36;

  float4 a[9];
#pragma unroll
  for (int k = 0; k < 8; ++k) a[k + 1] = *(const float4*)(p + k * 4);
  a[0] = (g > 0) ? *(const float4*)(p - 4)
                 : make_float4(-INFINITY, -INFINITY, -INFINITY, -INFINITY);
  __builtin_amdgcn_sched_barrier(0);     // keep all 9 loads issued first

  // window i covers rel [9i-4, 9i+5) -> flat regs a[0..8]
  float w0 = max9(a[0].x, a[0].y, a[0].z, a[0].w,
                  a[1].x, a[1].y, a[1].z, a[1].w, a[2].x);
  float w1 = max9(a[2].y, a[2].z, a[2].w,
                  a[3].x, a[3].y, a[3].z, a[3].w, a[4].x, a[4].y);
  float w2 = max9(a[4].z, a[4].w,
                  a[5].x, a[5].y, a[5].z, a[5].w, a[6].x, a[6].y, a[6].z);
  float w3 = max9(a[6].w,
                  a[7].x, a[7].y, a[7].z, a[7].w,
                  a[8].x, a[8].y, a[8].z, a[8].w);

  *(float4*)(dst + (size_t)row * LK + g * 4) = make_float4(w0, w1, w2, w3);
}

// ---------------------------------------------------------------------------
// K2: clustering head (identity-gather form).
// ---------------------------------------------------------------------------
__global__ __launch_bounds__(256) void cluster_kernel(
    const float* __restrict__ pK,
    const float* __restrict__ Wp,  const float* __restrict__ bp,
    const float* __restrict__ Wck, const float* __restrict__ bck,
    const float* __restrict__ Wcq, const float* __restrict__ bcq,
    float* __restrict__ cq_out, float* __restrict__ ck_out,
    float* __restrict__ loss_acc) {
  int bb = blockIdx.x / 9;
  int s  = blockIdx.x % 9;
  int tid = threadIdx.x;

  __shared__ float sK[256 * 33];
  __shared__ float sWp[1728];
  __shared__ float red[256];

  for (int i = tid; i < 1728; i += 256) sWp[i] = Wp[i];

  float a0 = 0.f, a1 = 0.f, a2 = 0.f;
  int umin = (bb >= 18) ? 0 : (18 - bb);

  for (int u = umin; u < 18; ++u) {
    int b2 = bb + u - 17;
    __syncthreads();
    const float4* src = (const float4*)(pK + (size_t)b2 * POOL_PER_B + s * 8192);
#pragma unroll
    for (int k = 0; k < 8; ++k) {
      int i = tid + k * 256;
      float4 v = src[i];
      int base = i * 4;
      float* dst = &sK[(base >> 5) * 33 + (base & 31)];
      dst[0] = v.x; dst[1] = v.y; dst[2] = v.z; dst[3] = v.w;
    }
    __syncthreads();
    const float* wrow = &sWp[u * 3];
    const float* krow = &sK[tid * 33];
#pragma unroll
    for (int g = 0; g < 32; ++g) {
      float v = krow[g];
      a0 = fmaf(v, wrow[g * 54 + 0], a0);
      a1 = fmaf(v, wrow[g * 54 + 1], a1);
      a2 = fmaf(v, wrow[g * 54 + 2], a2);
    }
  }

  float p0 = fmaxf(a0 + bp[0], 0.f);
  float p1 = fmaxf(a1 + bp[1], 0.f);
  float p2 = fmaxf(a2 + bp[2], 0.f);

  float k0 = p0 * Wck[0] + p1 * Wck[3] + p2 * Wck[6] + bck[0];
  float k1 = p0 * Wck[1] + p1 * Wck[4] + p2 * Wck[7] + bck[1];
  float k2 = p0 * Wck[2] + p1 * Wck[5] + p2 * Wck[8] + bck[2];
  float mk = fmaxf(k0, fmaxf(k1, k2));
  float e0 = __expf(k0 - mk), e1 = __expf(k1 - mk), e2 = __expf(k2 - mk);
  float inv = 1.f / (e0 + e1 + e2);
  float ck0 = e0 * inv, ck1 = e1 * inv, ck2 = e2 * inv;

  float q0 = p0 * Wcq[0] + p1 * Wcq[3] + p2 * Wcq[6] + bcq[0];
  float q1 = p0 * Wcq[1] + p1 * Wcq[4] + p2 * Wcq[7] + bcq[1];
  float q2 = p0 * Wcq[2] + p1 * Wcq[5] + p2 * Wcq[8] + bcq[2];
  float mq = fmaxf(q0, fmaxf(q1, q2));
  float f0 = __expf(q0 - mq), f1 = __expf(q1 - mq), f2 = __expf(q2 - mq);
  float invq = 1.f / (f0 + f1 + f2);
  float cq0 = f0 * invq, cq1 = f1 * invq, cq2 = f2 * invq;

  size_t t = (size_t)bb * 2304 + s * 256 + tid;
  ck_out[t * 3 + 0] = ck0;
  ck_out[t * 3 + 1] = ck1;
  ck_out[t * 3 + 2] = ck2;
  cq_out[t * 3 + 0] = cq0;
  cq_out[t * 3 + 1] = cq1;
  cq_out[t * 3 + 2] = cq2;

  float mean = (cq0 + cq1 + cq2) * (1.f / 3.f);
  float d0 = cq0 - mean, d1 = cq1 - mean, d2 = cq2 - mean;
  float var = (d0 * d0 + d1 * d1 + d2 * d2) * 0.5f;
  float sd  = sqrtf(var);
  float sig = log1pf(__expf(sd));
  float ls  = logf(sig);

  __syncthreads();
  red[tid] = ls;
  __syncthreads();
  for (int r = 128; r > 0; r >>= 1) {
    if (tid < r) red[tid] += red[tid + r];
    __syncthreads();
  }
  if (tid == 0) atomicAdd(loss_acc, red[0]);
}

// ---------------------------------------------------------------------------
// K3: per (bb, lk2): causal 18x18 attention + Wb head + disjoint maxpool.
// ---------------------------------------------------------------------------
__global__ __launch_bounds__(256) void center_kernel(
    const float* __restrict__ cq, const float* __restrict__ ck,
    const float* __restrict__ Wb, const float* __restrict__ bbias,
    float* __restrict__ ccpool) {
  int blk = blockIdx.x;
  int bb  = blk / LK;
  int lk2 = blk % LK;
  int tid = threadIdx.x;

  __shared__ float scq[54], sck[54], sq2[54];
  __shared__ float sWb[3 * 576];
  __shared__ float sbb[576];

  const float* cqb = cq + ((size_t)bb * (LK * B2) + (size_t)lk2 * B2) * 3;
  const float* ckb = ck + ((size_t)bb * (LK * B2) + (size_t)lk2 * B2) * 3;
  if (tid < 54) { scq[tid] = cqb[tid]; sck[tid] = ckb[tid]; }
  for (int i = tid; i < 1728; i += 256) sWb[i] = Wb[i];
  for (int i = tid; i < 576; i += 256) sbb[i] = bbias[i];
  __syncthreads();

  if (tid < B2) {
    int p = tid;
    float s[B2];
    float g0 = scq[p * 3 + 0], g1 = scq[p * 3 + 1], g2 = scq[p * 3 + 2];
    float mx = -INFINITY;
#pragma unroll
    for (int u = 0; u < B2; ++u) {
      float sv = (g0 * sck[u * 3] + g1 * sck[u * 3 + 1] + g2 * sck[u * 3 + 2]) *
                 (1.f / 3.f);
      if (u > p) sv = -1e9f;
      s[u] = sv;
      mx = fmaxf(mx, sv);
    }
    float sum = 0.f;
#pragma unroll
    for (int u = 0; u < B2; ++u) { s[u] = __expf(s[u] - mx); sum += s[u]; }
    float inv = 1.f / sum;
    float o0 = 0.f, o1 = 0.f, o2 = 0.f;
#pragma unroll
    for (int u = 0; u < B2; ++u) {
      float a = s[u] * inv;
      o0 = fmaf(a, scq[u * 3 + 0], o0);
      o1 = fmaf(a, scq[u * 3 + 1], o1);
      o2 = fmaf(a, scq[u * 3 + 2], o2);
    }
    sq2[p * 3 + 0] = o0; sq2[p * 3 + 1] = o1; sq2[p * 3 + 2] = o2;
  }
  __syncthreads();

  float* outb = ccpool + (size_t)bb * CCPOOL_PER_B + (size_t)lk2 * (B2 * 64);
  for (int i = tid; i < B2 * 64; i += 256) {
    int p = i >> 6;
    int w = i & 63;
    float g0 = sq2[p * 3 + 0], g1 = sq2[p * 3 + 1], g2 = sq2[p * 3 + 2];
    int t0 = w * 9 - 4;
    int lo = t0 < 0 ? 0 : t0;
    int hi = t0 + 8; if (hi > 575) hi = 575;
    float mxv = -INFINITY;
    for (int tt = lo; tt <= hi; ++tt) {
      float cv = g0 * sWb[tt] + g1 * sWb[576 + tt] + g2 * sWb[1152 + tt] + sbb[tt];
      cv = fmaxf(cv, 0.f);
      mxv = fmaxf(mxv, cv);
    }
    outb[i] = mxv;
  }
}

// ---------------------------------------------------------------------------
// K4a: prep MFMA operand fragments — bf16 (hi only) of Csum and Vp.
// Per-bh contiguous: Cfrag 1536 uint4, Vfrag 1280 uint4.
// ---------------------------------------------------------------------------
#define CFRAG_T (NBH*8*3*64)   // 442368
#define VFRAG_T (NBH*5*4*64)   // 368640
__global__ __launch_bounds__(256) void prep_kernel(
    const float* __restrict__ ccpool, const float* __restrict__ pV,
    uint4* __restrict__ Cfrag, uint4* __restrict__ Vfrag) {
  int t = blockIdx.x * 256 + threadIdx.x;   // 811008 exactly
  unsigned short hi[8];
  if (t < CFRAG_T) {
    int lane = t & 63;
    int rest = t >> 6;
    int ks = rest % 3;
    int mtb = rest / 3;
    int mt = mtb & 7;
    int bh = mtb >> 3;
    int bb = bh >> 3, hh = bh & 7;
    int key = mt * 16 + (lane & 15);
    int d0 = ks * 32 + (lane >> 4) * 8;
    const float* cp = ccpool + (size_t)bb * CCPOOL_PER_B + hh * 18432 + key * 72;
#pragma unroll
    for (int j = 0; j < 8; ++j) {
      int d = d0 + j;
      float v = (d < 72) ? (cp[d] + cp[9216 + d]) : 0.f;
      hi[j] = bf16_rne(v);
    }
    uint4 h4;
    h4.x = hi[0] | (hi[1] << 16); h4.y = hi[2] | (hi[3] << 16);
    h4.z = hi[4] | (hi[5] << 16); h4.w = hi[6] | (hi[7] << 16);
    Cfrag[t] = h4;
  } else {
    int t2 = t - CFRAG_T;
    int lane = t2 & 63;
    int rest = t2 >> 6;
    int ks = rest & 3;
    int ntb = rest >> 2;
    int nt = ntb % 5;
    int bh = ntb / 5;
    int d = nt * 16 + (lane & 15);
    int k0 = ks * 32 + (lane >> 4) * 8;
    const float* vp = pV + (size_t)bh * (LK * DK);
#pragma unroll
    for (int j = 0; j < 8; ++j) {
      int k = k0 + j;
      float v = (d < 72) ? vp[k * 72 + d] : 0.f;
      hi[j] = bf16_rne(v);
    }
    uint4 h4;
    h4.x = hi[0] | (hi[1] << 16); h4.y = hi[2] | (hi[3] << 16);
    h4.z = hi[4] | (hi[5] << 16); h4.w = hi[6] | (hi[7] << 16);
    Vfrag[t2] = h4;
  }
}

// ---------------------------------------------------------------------------
// K4b: MFMA attention (R8-proven config): 2 subtiles/wave, full 44 KB block-
// shared LDS staging of C+V fragments, bf16 Q, shfl-transposed P.
// ---------------------------------------------------------------------------
__global__ __launch_bounds__(256) void attn2_kernel(
    const float* __restrict__ Q, const uint4* __restrict__ Cfrag,
    const uint4* __restrict__ Vfrag, float* __restrict__ out) {
  __shared__ __align__(16) uint4 sFrag[2816];   // 44 KB: C [0,1536) V [1536,2816)

  int bh = blockIdx.x / 9, qt = blockIdx.x % 9;
  int tid = threadIdx.x;
  int wid = tid >> 6, lane = tid & 63;
  int lq = lane & 15, lg = lane >> 4;
  int qbase = qt * 128 + wid * 32;

  const uint4* gC = Cfrag + (size_t)bh * 1536;
  const uint4* gV = Vfrag + (size_t)bh * 1280;
#pragma unroll
  for (int k = 0; k < 6; ++k) sFrag[tid + k * 256] = gC[tid + k * 256];
#pragma unroll
  for (int k = 0; k < 5; ++k) sFrag[1536 + tid + k * 256] = gV[tid + k * 256];
  __syncthreads();

  f32x4 sacc[2][8];
#pragma unroll
  for (int s = 0; s < 2; ++s)
#pragma unroll
    for (int mt = 0; mt < 8; ++mt) sacc[s][mt] = (f32x4){0.f, 0.f, 0.f, 0.f};

  // ---- S^T = C * Q^T (bf16 Q) ----
#pragma unroll
  for (int ks = 0; ks < 3; ++ks) {
    short8 qh[2];
#pragma unroll
    for (int s = 0; s < 2; ++s) {
      int q = qbase + s * 16 + lq;
      const float* qrow = Q + ((size_t)bh * L + q) * DK;
      int d0 = ks * 32 + lg * 8;
      float x[8];
      if (ks < 2) {
        float4 a = *(const float4*)(qrow + d0);
        float4 b = *(const float4*)(qrow + d0 + 4);
        x[0] = a.x; x[1] = a.y; x[2] = a.z; x[3] = a.w;
        x[4] = b.x; x[5] = b.y; x[6] = b.z; x[7] = b.w;
      } else {
        if (lg == 0) {
          float4 a = *(const float4*)(qrow + 64);
          float4 b = *(const float4*)(qrow + 68);
          x[0] = a.x; x[1] = a.y; x[2] = a.z; x[3] = a.w;
          x[4] = b.x; x[5] = b.y; x[6] = b.z; x[7] = b.w;
        } else {
#pragma unroll
          for (int j = 0; j < 8; ++j) x[j] = 0.f;
        }
      }
#pragma unroll
      for (int j = 0; j < 8; ++j) qh[s][j] = (short)bf16_rne(x[j]);
    }
#pragma unroll
    for (int mt = 0; mt < 8; ++mt) {
      short8 chi = *(const short8*)&sFrag[(mt * 3 + ks) * 64 + lane];
#pragma unroll
      for (int s = 0; s < 2; ++s)
        sacc[s][mt] = __builtin_amdgcn_mfma_f32_16x16x32_bf16(chi, qh[s], sacc[s][mt], 0, 0, 0);
    }
  }

  // ---- softmax over keys (per q-col), normalized P packed as bf16 pairs ----
  unsigned pw[2][8][2];
#pragma unroll
  for (int s = 0; s < 2; ++s) {
    float mx = -INFINITY;
#pragma unroll
    for (int mt = 0; mt < 8; ++mt)
#pragma unroll
      for (int r = 0; r < 4; ++r) mx = fmaxf(mx, sacc[s][mt][r]);
    mx = fmaxf(mx, __shfl_xor(mx, 16));
    mx = fmaxf(mx, __shfl_xor(mx, 32));
    float sum = 0.f;
#pragma unroll
    for (int mt = 0; mt < 8; ++mt)
#pragma unroll
      for (int r = 0; r < 4; ++r) {
        float p = __expf(sacc[s][mt][r] - mx);
        sacc[s][mt][r] = p;
        sum += p;
      }
    sum += __shfl_xor(sum, 16);
    sum += __shfl_xor(sum, 32);
    float inv = 1.f / sum;
#pragma unroll
    for (int mt = 0; mt < 8; ++mt) {
      pw[s][mt][0] = pack2(sacc[s][mt][0] * inv, sacc[s][mt][1] * inv);
      pw[s][mt][1] = pack2(sacc[s][mt][2] * inv, sacc[s][mt][3] * inv);
    }
  }

  // ---- O = P * V via shfl transpose ----
  f32x4 oacc[2][5];
#pragma unroll
  for (int s = 0; s < 2; ++s)
#pragma unroll
    for (int nt = 0; nt < 5; ++nt) oacc[s][nt] = (f32x4){0.f, 0.f, 0.f, 0.f};

  int baseA = lq + 32 * (lg & 1);
  int baseB = baseA + 16;
  bool hiGrp = (lg & 2) != 0;

#pragma unroll
  for (int ks = 0; ks < 4; ++ks) {
    short8 pa[2];
#pragma unroll
    for (int s = 0; s < 2; ++s) {
      unsigned a0 = pw[s][2 * ks][0],     a1 = pw[s][2 * ks][1];
      unsigned b0 = pw[s][2 * ks + 1][0], b1 = pw[s][2 * ks + 1][1];
      unsigned r00 = __shfl(a0, baseA, 64), r10 = __shfl(b0, baseA, 64);
      unsigned r01 = __shfl(a1, baseA, 64), r11 = __shfl(b1, baseA, 64);
      unsigned r02 = __shfl(a0, baseB, 64), r12 = __shfl(b0, baseB, 64);
      unsigned r03 = __shfl(a1, baseB, 64), r13 = __shfl(b1, baseB, 64);
      uint4 u;
      u.x = hiGrp ? r10 : r00;
      u.y = hiGrp ? r11 : r01;
      u.z = hiGrp ? r12 : r02;
      u.w = hiGrp ? r13 : r03;
      pa[s] = *(short8*)&u;
    }
#pragma unroll
    for (int nt = 0; nt < 5; ++nt) {
      short8 vhi = *(const short8*)&sFrag[1536 + (nt * 4 + ks) * 64 + lane];
#pragma unroll
      for (int s = 0; s < 2; ++s)
        oacc[s][nt] = __builtin_amdgcn_mfma_f32_16x16x32_bf16(pa[s], vhi, oacc[s][nt], 0, 0, 0);
    }
  }

  // ---- store: D layout col=lane&15 (d), row=(lane>>4)*4+r (q) ----
#pragma unroll
  for (int s = 0; s < 2; ++s) {
#pragma unroll
    for (int nt = 0; nt < 5; ++nt) {
      int d = nt * 16 + lq;
      if (d < 72) {
        float* orow = out + ((size_t)bh * L + qbase + s * 16 + lg * 4) * DK + d;
#pragma unroll
        for (int r = 0; r < 4; ++r) orow[(size_t)r * DK] = oacc[s][nt][r];
      }
    }
  }
}

// ---------------------------------------------------------------------------
// K5: finalize loss (mu == xk == 1/3 exactly; ce is a constant).
// ---------------------------------------------------------------------------
__global__ void finalize_kernel(const float* __restrict__ loss_acc,
                                float* __restrict__ out_loss) {
  *out_loss = loss_acc[0] * (1.f / 82944.f) + 207.93889646f;
}

extern "C" void kernel_launch(void* const* d_in, const int* in_sizes, int n_in,
                              void* d_out, int out_size, void* d_ws, size_t ws_size,
                              hipStream_t stream) {
  const float* Q    = (const float*)d_in[0];
  const float* Kin  = (const float*)d_in[1];
  const float* Vin  = (const float*)d_in[2];
  const float* Wp   = (const float*)d_in[3];
  const float* bp   = (const float*)d_in[4];
  const float* Wck  = (const float*)d_in[5];
  const float* bck  = (const float*)d_in[6];
  const float* Wcq  = (const float*)d_in[7];
  const float* bcq  = (const float*)d_in[8];
  const float* Wb   = (const float*)d_in[9];
  const float* bbv  = (const float*)d_in[10];
  float* out = (float*)d_out;

  float* ws = (float*)d_ws;
  float* pK       = ws;
  float* pV       = pK + POOL_TOTAL;
  float* cq       = pV + POOL_TOTAL;
  float* ck       = cq + (size_t)CLUS_TOTAL * 3;
  float* ccpool   = ck + (size_t)CLUS_TOTAL * 3;
  float* cfrag_f  = ccpool + (size_t)BATCH * CCPOOL_PER_B;
  uint4* Cfrag    = (uint4*)cfrag_f;
  uint4* Vfrag    = Cfrag + (size_t)CFRAG_T;
  float* loss_acc = (float*)(Vfrag + (size_t)VFRAG_T);

  hipMemsetAsync(loss_acc, 0, sizeof(float), stream);

  pool_kernel<<<2 * (BATCH * DM) * 32 / 256, 256, 0, stream>>>(Kin, Vin, pK, pV);
  cluster_kernel<<<BATCH * 9, 256, 0, stream>>>(
      pK, Wp, bp, Wck, bck, Wcq, bcq, cq, ck, loss_acc);
  center_kernel<<<BATCH * LK, 256, 0, stream>>>(cq, ck, Wb, bbv, ccpool);
  prep_kernel<<<(CFRAG_T + VFRAG_T) / 256, 256, 0, stream>>>(ccpool, pV, Cfrag, Vfrag);
  attn2_kernel<<<NBH * 9, 256, 0, stream>>>(Q, Cfrag, Vfrag, out);
  finalize_kernel<<<1, 1, 0, stream>>>(loss_acc, out + CTX_ELEMS);
}

// Round 12
// 183.989 us; speedup vs baseline: 1.0668x; 1.0620x over previous
//
#include <hip/hip_runtime.h>
#include <math.h>

#define BATCH 36
#define H 8
#define L 1152
#define DK 72
#define DM 576
#define LK 128
#define B2 18
#define NC 3

// derived
#define POOL_PER_B (DM*LK)            // 73728
#define POOL_TOTAL (BATCH*POOL_PER_B) // 2654208
#define CLUS_TOTAL (BATCH*LK*B2)      // 82944
#define CTX_ELEMS (BATCH*H*L*DK)      // 23887872
#define NBH (BATCH*H)                 // 288

typedef __attribute__((ext_vector_type(8))) short short8;
typedef __attribute__((ext_vector_type(4))) float f32x4;

// round-to-nearest-even fp32 -> bf16 bits
__device__ __forceinline__ unsigned short bf16_rne(float x) {
  unsigned u = __float_as_uint(x);
  unsigned r = u + 0x7FFFu + ((u >> 16) & 1u);
  return (unsigned short)(r >> 16);
}
__device__ __forceinline__ unsigned pack2(float a, float b) {
  return (unsigned)bf16_rne(a) | ((unsigned)bf16_rne(b) << 16);
}
__device__ __forceinline__ float max9(float x0, float x1, float x2, float x3,
                                      float x4, float x5, float x6, float x7,
                                      float x8) {
  float m0 = fmaxf(fmaxf(x0, x1), x2);
  float m1 = fmaxf(fmaxf(x3, x4), x5);
  float m2 = fmaxf(fmaxf(x6, x7), x8);
  return fmaxf(fmaxf(m0, m1), m2);
}

// ---------------------------------------------------------------------------
// K1: MaxPool1d(kernel=9, stride=9, pad=4) — register-blocked (R11 config;
// measured at the ~3 TB/s empirical service wall, 70us).
// ---------------------------------------------------------------------------
__global__ __launch_bounds__(256, 8) void pool_kernel(
    const float* __restrict__ Kin, const float* __restrict__ Vin,
    float* __restrict__ pK, float* __restrict__ pV) {
  int t = blockIdx.x * 256 + threadIdx.x;
  const int perT = (BATCH * DM) * 32;    // 663552 groups per tensor
  const float* src;
  float* dst;
  if (t < perT) {
    src = Kin; dst = pK;
  } else {
    src = Vin; dst = pV; t -= perT;
  }
  int row = t >> 5, g = t & 31;
  const float* p = src + (size_t)row * L + g * 36;

  float4 a[9];
#pragma unroll
  for (int k = 0; k < 8; ++k) a[k + 1] = *(const float4*)(p + k * 4);
  a[0] = (g > 0) ? *(const float4*)(p - 4)
                 : make_float4(-INFINITY, -INFINITY, -INFINITY, -INFINITY);
  __builtin_amdgcn_sched_barrier(0);

  float w0 = max9(a[0].x, a[0].y, a[0].z, a[0].w,
                  a[1].x, a[1].y, a[1].z, a[1].w, a[2].x);
  float w1 = max9(a[2].y, a[2].z, a[2].w,
                  a[3].x, a[3].y, a[3].z, a[3].w, a[4].x, a[4].y);
  float w2 = max9(a[4].z, a[4].w,
                  a[5].x, a[5].y, a[5].z, a[5].w, a[6].x, a[6].y, a[6].z);
  float w3 = max9(a[6].w,
                  a[7].x, a[7].y, a[7].z, a[7].w,
                  a[8].x, a[8].y, a[8].z, a[8].w);

  *(float4*)(dst + (size_t)row * LK + g * 4) = make_float4(w0, w1, w2, w3);
}

// ---------------------------------------------------------------------------
// K2: clustering head (identity-gather form).
// ---------------------------------------------------------------------------
__global__ __launch_bounds__(256) void cluster_kernel(
    const float* __restrict__ pK,
    const float* __restrict__ Wp,  const float* __restrict__ bp,
    const float* __restrict__ Wck, const float* __restrict__ bck,
    const float* __restrict__ Wcq, const float* __restrict__ bcq,
    float* __restrict__ cq_out, float* __restrict__ ck_out,
    float* __restrict__ loss_acc) {
  int bb = blockIdx.x / 9;
  int s  = blockIdx.x % 9;
  int tid = threadIdx.x;

  __shared__ float sK[256 * 33];
  __shared__ float sWp[1728];
  __shared__ float red[256];

  for (int i = tid; i < 1728; i += 256) sWp[i] = Wp[i];

  float a0 = 0.f, a1 = 0.f, a2 = 0.f;
  int umin = (bb >= 18) ? 0 : (18 - bb);

  for (int u = umin; u < 18; ++u) {
    int b2 = bb + u - 17;
    __syncthreads();
    const float4* src = (const float4*)(pK + (size_t)b2 * POOL_PER_B + s * 8192);
#pragma unroll
    for (int k = 0; k < 8; ++k) {
      int i = tid + k * 256;
      float4 v = src[i];
      int base = i * 4;
      float* dst = &sK[(base >> 5) * 33 + (base & 31)];
      dst[0] = v.x; dst[1] = v.y; dst[2] = v.z; dst[3] = v.w;
    }
    __syncthreads();
    const float* wrow = &sWp[u * 3];
    const float* krow = &sK[tid * 33];
#pragma unroll
    for (int g = 0; g < 32; ++g) {
      float v = krow[g];
      a0 = fmaf(v, wrow[g * 54 + 0], a0);
      a1 = fmaf(v, wrow[g * 54 + 1], a1);
      a2 = fmaf(v, wrow[g * 54 + 2], a2);
    }
  }

  float p0 = fmaxf(a0 + bp[0], 0.f);
  float p1 = fmaxf(a1 + bp[1], 0.f);
  float p2 = fmaxf(a2 + bp[2], 0.f);

  float k0 = p0 * Wck[0] + p1 * Wck[3] + p2 * Wck[6] + bck[0];
  float k1 = p0 * Wck[1] + p1 * Wck[4] + p2 * Wck[7] + bck[1];
  float k2 = p0 * Wck[2] + p1 * Wck[5] + p2 * Wck[8] + bck[2];
  float mk = fmaxf(k0, fmaxf(k1, k2));
  float e0 = __expf(k0 - mk), e1 = __expf(k1 - mk), e2 = __expf(k2 - mk);
  float inv = 1.f / (e0 + e1 + e2);
  float ck0 = e0 * inv, ck1 = e1 * inv, ck2 = e2 * inv;

  float q0 = p0 * Wcq[0] + p1 * Wcq[3] + p2 * Wcq[6] + bcq[0];
  float q1 = p0 * Wcq[1] + p1 * Wcq[4] + p2 * Wcq[7] + bcq[1];
  float q2 = p0 * Wcq[2] + p1 * Wcq[5] + p2 * Wcq[8] + bcq[2];
  float mq = fmaxf(q0, fmaxf(q1, q2));
  float f0 = __expf(q0 - mq), f1 = __expf(q1 - mq), f2 = __expf(q2 - mq);
  float invq = 1.f / (f0 + f1 + f2);
  float cq0 = f0 * invq, cq1 = f1 * invq, cq2 = f2 * invq;

  size_t t = (size_t)bb * 2304 + s * 256 + tid;
  ck_out[t * 3 + 0] = ck0;
  ck_out[t * 3 + 1] = ck1;
  ck_out[t * 3 + 2] = ck2;
  cq_out[t * 3 + 0] = cq0;
  cq_out[t * 3 + 1] = cq1;
  cq_out[t * 3 + 2] = cq2;

  float mean = (cq0 + cq1 + cq2) * (1.f / 3.f);
  float d0 = cq0 - mean, d1 = cq1 - mean, d2 = cq2 - mean;
  float var = (d0 * d0 + d1 * d1 + d2 * d2) * 0.5f;
  float sd  = sqrtf(var);
  float sig = log1pf(__expf(sd));
  float ls  = logf(sig);

  __syncthreads();
  red[tid] = ls;
  __syncthreads();
  for (int r = 128; r > 0; r >>= 1) {
    if (tid < r) red[tid] += red[tid + r];
    __syncthreads();
  }
  if (tid == 0) atomicAdd(loss_acc, red[0]);
}

// ---------------------------------------------------------------------------
// K3: FUSED center+prepC. Block = (bb, hh, mt): owns lk2 pair (L0=hh*16+mt,
// L1=L0+8). Index identity: Cfrag subtile (bh,mt) needs Csum[key][d] =
// cc[hh*18432+key*72+d] + cc[+9216]; lk2(j) = hh*16+key/16 = hh*16+mt and the
// +9216 partner is lk2+8 at the SAME intra-lk2 offset kk*72+d (= p*64+w).
// So: compute both lk2 (18x18 attention + Wb relu + disjoint maxpool) into
// LDS, pairwise-sum, emit Cfrag bf16 directly. ccpool never materializes.
// ---------------------------------------------------------------------------
__global__ __launch_bounds__(256) void center2_kernel(
    const float* __restrict__ cq, const float* __restrict__ ck,
    const float* __restrict__ Wb, const float* __restrict__ bbias,
    uint4* __restrict__ Cfrag) {
  int bid = blockIdx.x;                 // (bb*8+hh)*8+mt
  int mt = bid & 7, hh = (bid >> 3) & 7, bb = bid >> 6;
  int L0 = hh * 16 + mt;
  int tid = threadIdx.x;

  __shared__ float sWb[1728];
  __shared__ float sbb[576];
  __shared__ float scq[2][54], sck[2][54], sq2[2][54];
  __shared__ float pooled[2][1152];

  for (int i = tid; i < 1728; i += 256) sWb[i] = Wb[i];
  for (int i = tid; i < 576; i += 256) sbb[i] = bbias[i];
  if (tid < 108) {
    int h2 = tid / 54, r = tid % 54;
    int Lx = L0 + h2 * 8;
    const float* cqb = cq + ((size_t)bb * 2304 + Lx * 18) * 3;
    const float* ckb = ck + ((size_t)bb * 2304 + Lx * 18) * 3;
    scq[h2][r] = cqb[r];
    sck[h2][r] = ckb[r];
  }
  __syncthreads();

  // two 18x18 causal attentions: warp 0 -> L0, warp 1 -> L1
  {
    int h2 = tid >> 6;
    int p  = tid & 63;
    if (h2 < 2 && p < B2) {
      float s[B2];
      float g0 = scq[h2][p * 3 + 0], g1 = scq[h2][p * 3 + 1], g2 = scq[h2][p * 3 + 2];
      float mx = -INFINITY;
#pragma unroll
      for (int u = 0; u < B2; ++u) {
        float sv = (g0 * sck[h2][u * 3] + g1 * sck[h2][u * 3 + 1] +
                    g2 * sck[h2][u * 3 + 2]) * (1.f / 3.f);
        if (u > p) sv = -1e9f;
        s[u] = sv;
        mx = fmaxf(mx, sv);
      }
      float sum = 0.f;
#pragma unroll
      for (int u = 0; u < B2; ++u) { s[u] = __expf(s[u] - mx); sum += s[u]; }
      float inv = 1.f / sum;
      float o0 = 0.f, o1 = 0.f, o2 = 0.f;
#pragma unroll
      for (int u = 0; u < B2; ++u) {
        float a = s[u] * inv;
        o0 = fmaf(a, scq[h2][u * 3 + 0], o0);
        o1 = fmaf(a, scq[h2][u * 3 + 1], o1);
        o2 = fmaf(a, scq[h2][u * 3 + 2], o2);
      }
      sq2[h2][p * 3 + 0] = o0; sq2[h2][p * 3 + 1] = o1; sq2[h2][p * 3 + 2] = o2;
    }
  }
  __syncthreads();

  // pooled[h2][p*64+w] for both lk2: 2304 outputs, 9/thread
  for (int i = tid; i < 2 * 1152; i += 256) {
    int h2 = i / 1152, r = i % 1152;
    int p = r >> 6, w = r & 63;
    float g0 = sq2[h2][p * 3 + 0], g1 = sq2[h2][p * 3 + 1], g2 = sq2[h2][p * 3 + 2];
    int t0 = w * 9 - 4;
    int lo = t0 < 0 ? 0 : t0;
    int hi = t0 + 8; if (hi > 575) hi = 575;
    float mxv = -INFINITY;
    for (int tt = lo; tt <= hi; ++tt) {
      float cv = g0 * sWb[tt] + g1 * sWb[576 + tt] + g2 * sWb[1152 + tt] + sbb[tt];
      cv = fmaxf(cv, 0.f);
      mxv = fmaxf(mxv, cv);
    }
    pooled[h2][r] = mxv;
  }
  __syncthreads();

  // Csum_flat[i] = pooled[0][i] + pooled[1][i];  key = mt*16 + i/72, d = i%72
  // Cfrag write: t = ((bh*8+mt)*3+ks)*64+lane; value j: kk=lane&15,
  // d = ks*32+(lane>>4)*8+j
  if (tid < 192) {
    int ks = tid >> 6, lane = tid & 63;
    int kk = lane & 15;
    int d0 = ks * 32 + ((lane >> 4) << 3);
    unsigned short hi8[8];
#pragma unroll
    for (int j = 0; j < 8; ++j) {
      int d = d0 + j;
      float v = 0.f;
      if (d < 72) {
        int idx = kk * 72 + d;
        v = pooled[0][idx] + pooled[1][idx];
      }
      hi8[j] = bf16_rne(v);
    }
    uint4 h4;
    h4.x = hi8[0] | (hi8[1] << 16); h4.y = hi8[2] | (hi8[3] << 16);
    h4.z = hi8[4] | (hi8[5] << 16); h4.w = hi8[6] | (hi8[7] << 16);
    int bh = bb * 8 + hh;
    Cfrag[(((size_t)bh * 8 + mt) * 3 + ks) * 64 + lane] = h4;
  }
}

// ---------------------------------------------------------------------------
// K4: prep V fragments only (bf16 of Vp in MFMA B layout) + loss finalize.
// ---------------------------------------------------------------------------
#define CFRAG_T (NBH*8*3*64)   // 442368
#define VFRAG_T (NBH*5*4*64)   // 368640
__global__ __launch_bounds__(256) void prep_v_kernel(
    const float* __restrict__ pV, uint4* __restrict__ Vfrag,
    const float* __restrict__ loss_acc, float* __restrict__ out_loss) {
  int t2 = blockIdx.x * 256 + threadIdx.x;   // VFRAG_T exactly
  if (t2 == 0)
    *out_loss = loss_acc[0] * (1.f / 82944.f) + 207.93889646f;
  int lane = t2 & 63;
  int rest = t2 >> 6;
  int ks = rest & 3;
  int ntb = rest >> 2;
  int nt = ntb % 5;
  int bh = ntb / 5;
  int d = nt * 16 + (lane & 15);
  int k0 = ks * 32 + (lane >> 4) * 8;
  const float* vp = pV + (size_t)bh * (LK * DK);
  unsigned short hi8[8];
#pragma unroll
  for (int j = 0; j < 8; ++j) {
    int k = k0 + j;
    float v = (d < 72) ? vp[k * 72 + d] : 0.f;
    hi8[j] = bf16_rne(v);
  }
  uint4 h4;
  h4.x = hi8[0] | (hi8[1] << 16); h4.y = hi8[2] | (hi8[3] << 16);
  h4.z = hi8[4] | (hi8[5] << 16); h4.w = hi8[6] | (hi8[7] << 16);
  Vfrag[t2] = h4;
}

// ---------------------------------------------------------------------------
// K5: MFMA attention (R8-proven config): 2 subtiles/wave, full 44 KB block-
// shared LDS staging of C+V fragments, bf16 Q, shfl-transposed P.
// ---------------------------------------------------------------------------
__global__ __launch_bounds__(256) void attn2_kernel(
    const float* __restrict__ Q, const uint4* __restrict__ Cfrag,
    const uint4* __restrict__ Vfrag, float* __restrict__ out) {
  __shared__ __align__(16) uint4 sFrag[2816];   // 44 KB: C [0,1536) V [1536,2816)

  int bh = blockIdx.x / 9, qt = blockIdx.x % 9;
  int tid = threadIdx.x;
  int wid = tid >> 6, lane = tid & 63;
  int lq = lane & 15, lg = lane >> 4;
  int qbase = qt * 128 + wid * 32;

  const uint4* gC = Cfrag + (size_t)bh * 1536;
  const uint4* gV = Vfrag + (size_t)bh * 1280;
#pragma unroll
  for (int k = 0; k < 6; ++k) sFrag[tid + k * 256] = gC[tid + k * 256];
#pragma unroll
  for (int k = 0; k < 5; ++k) sFrag[1536 + tid + k * 256] = gV[tid + k * 256];
  __syncthreads();

  f32x4 sacc[2][8];
#pragma unroll
  for (int s = 0; s < 2; ++s)
#pragma unroll
    for (int mt = 0; mt < 8; ++mt) sacc[s][mt] = (f32x4){0.f, 0.f, 0.f, 0.f};

  // ---- S^T = C * Q^T (bf16 Q) ----
#pragma unroll
  for (int ks = 0; ks < 3; ++ks) {
    short8 qh[2];
#pragma unroll
    for (int s = 0; s < 2; ++s) {
      int q = qbase + s * 16 + lq;
      const float* qrow = Q + ((size_t)bh * L + q) * DK;
      int d0 = ks * 32 + lg * 8;
      float x[8];
      if (ks < 2) {
        float4 a = *(const float4*)(qrow + d0);
        float4 b = *(const float4*)(qrow + d0 + 4);
        x[0] = a.x; x[1] = a.y; x[2] = a.z; x[3] = a.w;
        x[4] = b.x; x[5] = b.y; x[6] = b.z; x[7] = b.w;
      } else {
        if (lg == 0) {
          float4 a = *(const float4*)(qrow + 64);
          float4 b = *(const float4*)(qrow + 68);
          x[0] = a.x; x[1] = a.y; x[2] = a.z; x[3] = a.w;
          x[4] = b.x; x[5] = b.y; x[6] = b.z; x[7] = b.w;
        } else {
#pragma unroll
          for (int j = 0; j < 8; ++j) x[j] = 0.f;
        }
      }
#pragma unroll
      for (int j = 0; j < 8; ++j) qh[s][j] = (short)bf16_rne(x[j]);
    }
#pragma unroll
    for (int mt = 0; mt < 8; ++mt) {
      short8 chi = *(const short8*)&sFrag[(mt * 3 + ks) * 64 + lane];
#pragma unroll
      for (int s = 0; s < 2; ++s)
        sacc[s][mt] = __builtin_amdgcn_mfma_f32_16x16x32_bf16(chi, qh[s], sacc[s][mt], 0, 0, 0);
    }
  }

  // ---- softmax over keys (per q-col), normalized P packed as bf16 pairs ----
  unsigned pw[2][8][2];
#pragma unroll
  for (int s = 0; s < 2; ++s) {
    float mx = -INFINITY;
#pragma unroll
    for (int mt = 0; mt < 8; ++mt)
#pragma unroll
      for (int r = 0; r < 4; ++r) mx = fmaxf(mx, sacc[s][mt][r]);
    mx = fmaxf(mx, __shfl_xor(mx, 16));
    mx = fmaxf(mx, __shfl_xor(mx, 32));
    float sum = 0.f;
#pragma unroll
    for (int mt = 0; mt < 8; ++mt)
#pragma unroll
      for (int r = 0; r < 4; ++r) {
        float p = __expf(sacc[s][mt][r] - mx);
        sacc[s][mt][r] = p;
        sum += p;
      }
    sum += __shfl_xor(sum, 16);
    sum += __shfl_xor(sum, 32);
    float inv = 1.f / sum;
#pragma unroll
    for (int mt = 0; mt < 8; ++mt) {
      pw[s][mt][0] = pack2(sacc[s][mt][0] * inv, sacc[s][mt][1] * inv);
      pw[s][mt][1] = pack2(sacc[s][mt][2] * inv, sacc[s][mt][3] * inv);
    }
  }

  // ---- O = P * V via shfl transpose ----
  f32x4 oacc[2][5];
#pragma unroll
  for (int s = 0; s < 2; ++s)
#pragma unroll
    for (int nt = 0; nt < 5; ++nt) oacc[s][nt] = (f32x4){0.f, 0.f, 0.f, 0.f};

  int baseA = lq + 32 * (lg & 1);
  int baseB = baseA + 16;
  bool hiGrp = (lg & 2) != 0;

#pragma unroll
  for (int ks = 0; ks < 4; ++ks) {
    short8 pa[2];
#pragma unroll
    for (int s = 0; s < 2; ++s) {
      unsigned a0 = pw[s][2 * ks][0],     a1 = pw[s][2 * ks][1];
      unsigned b0 = pw[s][2 * ks + 1][0], b1 = pw[s][2 * ks + 1][1];
      unsigned r00 = __shfl(a0, baseA, 64), r10 = __shfl(b0, baseA, 64);
      unsigned r01 = __shfl(a1, baseA, 64), r11 = __shfl(b1, baseA, 64);
      unsigned r02 = __shfl(a0, baseB, 64), r12 = __shfl(b0, baseB, 64);
      unsigned r03 = __shfl(a1, baseB, 64), r13 = __shfl(b1, baseB, 64);
      uint4 u;
      u.x = hiGrp ? r10 : r00;
      u.y = hiGrp ? r11 : r01;
      u.z = hiGrp ? r12 : r02;
      u.w = hiGrp ? r13 : r03;
      pa[s] = *(short8*)&u;
    }
#pragma unroll
    for (int nt = 0; nt < 5; ++nt) {
      short8 vhi = *(const short8*)&sFrag[1536 + (nt * 4 + ks) * 64 + lane];
#pragma unroll
      for (int s = 0; s < 2; ++s)
        oacc[s][nt] = __builtin_amdgcn_mfma_f32_16x16x32_bf16(pa[s], vhi, oacc[s][nt], 0, 0, 0);
    }
  }

  // ---- store: D layout col=lane&15 (d), row=(lane>>4)*4+r (q) ----
#pragma unroll
  for (int s = 0; s < 2; ++s) {
#pragma unroll
    for (int nt = 0; nt < 5; ++nt) {
      int d = nt * 16 + lq;
      if (d < 72) {
        float* orow = out + ((size_t)bh * L + qbase + s * 16 + lg * 4) * DK + d;
#pragma unroll
        for (int r = 0; r < 4; ++r) orow[(size_t)r * DK] = oacc[s][nt][r];
      }
    }
  }
}

extern "C" void kernel_launch(void* const* d_in, const int* in_sizes, int n_in,
                              void* d_out, int out_size, void* d_ws, size_t ws_size,
                              hipStream_t stream) {
  const float* Q    = (const float*)d_in[0];
  const float* Kin  = (const float*)d_in[1];
  const float* Vin  = (const float*)d_in[2];
  const float* Wp   = (const float*)d_in[3];
  const float* bp   = (const float*)d_in[4];
  const float* Wck  = (const float*)d_in[5];
  const float* bck  = (const float*)d_in[6];
  const float* Wcq  = (const float*)d_in[7];
  const float* bcq  = (const float*)d_in[8];
  const float* Wb   = (const float*)d_in[9];
  const float* bbv  = (const float*)d_in[10];
  float* out = (float*)d_out;

  float* ws = (float*)d_ws;
  float* pK       = ws;
  float* pV       = pK + POOL_TOTAL;
  float* cq       = pV + POOL_TOTAL;
  float* ck       = cq + (size_t)CLUS_TOTAL * 3;
  uint4* Cfrag    = (uint4*)(ck + (size_t)CLUS_TOTAL * 3);
  uint4* Vfrag    = Cfrag + (size_t)CFRAG_T;
  float* loss_acc = (float*)(Vfrag + (size_t)VFRAG_T);

  hipMemsetAsync(loss_acc, 0, sizeof(float), stream);

  pool_kernel<<<2 * (BATCH * DM) * 32 / 256, 256, 0, stream>>>(Kin, Vin, pK, pV);
  cluster_kernel<<<BATCH * 9, 256, 0, stream>>>(
      pK, Wp, bp, Wck, bck, Wcq, bcq, cq, ck, loss_acc);
  center2_kernel<<<BATCH * 64, 256, 0, stream>>>(cq, ck, Wb, bbv, Cfrag);
  prep_v_kernel<<<VFRAG_T / 256, 256, 0, stream>>>(
      pV, Vfrag, loss_acc, out + CTX_ELEMS);
  attn2_kernel<<<NBH * 9, 256, 0, stream>>>(Q, Cfrag, Vfrag, out);
}

// Round 13
// 180.442 us; speedup vs baseline: 1.0878x; 1.0197x over previous
//
#include <hip/hip_runtime.h>
#include <math.h>

#define BATCH 36
#define H 8
#define L 1152
#define DK 72
#define DM 576
#define LK 128
#define B2 18
#define NC 3

// derived
#define POOL_PER_B (DM*LK)            // 73728
#define POOL_TOTAL (BATCH*POOL_PER_B) // 2654208
#define CLUS_TOTAL (BATCH*LK*B2)      // 82944
#define CTX_ELEMS (BATCH*H*L*DK)      // 23887872
#define NBH (BATCH*H)                 // 288
#define CFRAG_T (NBH*8*3*64)          // 442368
#define VFRAG_T (NBH*5*4*64)          // 368640

typedef __attribute__((ext_vector_type(8))) short short8;
typedef __attribute__((ext_vector_type(4))) float f32x4;

// round-to-nearest-even fp32 -> bf16 bits
__device__ __forceinline__ unsigned short bf16_rne(float x) {
  unsigned u = __float_as_uint(x);
  unsigned r = u + 0x7FFFu + ((u >> 16) & 1u);
  return (unsigned short)(r >> 16);
}
__device__ __forceinline__ unsigned pack2(float a, float b) {
  return (unsigned)bf16_rne(a) | ((unsigned)bf16_rne(b) << 16);
}
__device__ __forceinline__ float max9(float x0, float x1, float x2, float x3,
                                      float x4, float x5, float x6, float x7,
                                      float x8) {
  float m0 = fmaxf(fmaxf(x0, x1), x2);
  float m1 = fmaxf(fmaxf(x3, x4), x5);
  float m2 = fmaxf(fmaxf(x6, x7), x8);
  return fmaxf(fmaxf(m0, m1), m2);
}

// ---------------------------------------------------------------------------
// K1: MaxPool1d(kernel=9, stride=9, pad=4) — register-blocked.
// K-half -> pK (fp32, consumed 18x by cluster).
// V-half -> Vfrag DIRECTLY (bf16 MFMA B-fragment layout): thread (row,g)
// holds windows k=4g..4g+3 at fixed (bh,d); index algebra maps them to one
// aligned uint2 (half of the Vfrag uint4): lane=((g&7)>>1)<<4|(d&15),
// ks=g>>3, half=g&1 (j=4*half+0..3 <-> k=4g+0..3). pV and prep_v eliminated;
// d>=72 pad slots pre-zeroed by hipMemsetAsync.
// ---------------------------------------------------------------------------
__global__ __launch_bounds__(256, 8) void pool_kernel(
    const float* __restrict__ Kin, const float* __restrict__ Vin,
    float* __restrict__ pK, uint2* __restrict__ Vfrag2) {
  int t = blockIdx.x * 256 + threadIdx.x;
  const int perT = (BATCH * DM) * 32;    // 663552 groups per tensor
  bool isK = t < perT;
  const float* src;
  if (isK) {
    src = Kin;
  } else {
    src = Vin; t -= perT;
  }
  int row = t >> 5, g = t & 31;
  const float* p = src + (size_t)row * L + g * 36;

  float4 a[9];
#pragma unroll
  for (int k = 0; k < 8; ++k) a[k + 1] = *(const float4*)(p + k * 4);
  a[0] = (g > 0) ? *(const float4*)(p - 4)
                 : make_float4(-INFINITY, -INFINITY, -INFINITY, -INFINITY);
  __builtin_amdgcn_sched_barrier(0);

  float w0 = max9(a[0].x, a[0].y, a[0].z, a[0].w,
                  a[1].x, a[1].y, a[1].z, a[1].w, a[2].x);
  float w1 = max9(a[2].y, a[2].z, a[2].w,
                  a[3].x, a[3].y, a[3].z, a[3].w, a[4].x, a[4].y);
  float w2 = max9(a[4].z, a[4].w,
                  a[5].x, a[5].y, a[5].z, a[5].w, a[6].x, a[6].y, a[6].z);
  float w3 = max9(a[6].w,
                  a[7].x, a[7].y, a[7].z, a[7].w,
                  a[8].x, a[8].y, a[8].z, a[8].w);

  if (isK) {
    *(float4*)(pK + (size_t)row * LK + g * 4) = make_float4(w0, w1, w2, w3);
  } else {
    int bb = row / DM, m = row % DM;
    int hh = m / DK, d = m % DK;
    int bh = bb * 8 + hh;
    int nt = d >> 4, dl = d & 15;
    int ks = g >> 3, sub = (g & 7) >> 1, half = g & 1;
    int lane = (sub << 4) | dl;
    size_t u4 = (((size_t)bh * 5 + nt) * 4 + ks) * 64 + lane;
    Vfrag2[u4 * 2 + half] = make_uint2(pack2(w0, w1), pack2(w2, w3));
  }
}

// ---------------------------------------------------------------------------
// K2: clustering head (identity-gather form).
// ---------------------------------------------------------------------------
__global__ __launch_bounds__(256) void cluster_kernel(
    const float* __restrict__ pK,
    const float* __restrict__ Wp,  const float* __restrict__ bp,
    const float* __restrict__ Wck, const float* __restrict__ bck,
    const float* __restrict__ Wcq, const float* __restrict__ bcq,
    float* __restrict__ cq_out, float* __restrict__ ck_out,
    float* __restrict__ loss_acc) {
  int bb = blockIdx.x / 9;
  int s  = blockIdx.x % 9;
  int tid = threadIdx.x;

  __shared__ float sK[256 * 33];
  __shared__ float sWp[1728];
  __shared__ float red[256];

  for (int i = tid; i < 1728; i += 256) sWp[i] = Wp[i];

  float a0 = 0.f, a1 = 0.f, a2 = 0.f;
  int umin = (bb >= 18) ? 0 : (18 - bb);

  for (int u = umin; u < 18; ++u) {
    int b2 = bb + u - 17;
    __syncthreads();
    const float4* src = (const float4*)(pK + (size_t)b2 * POOL_PER_B + s * 8192);
#pragma unroll
    for (int k = 0; k < 8; ++k) {
      int i = tid + k * 256;
      float4 v = src[i];
      int base = i * 4;
      float* dst = &sK[(base >> 5) * 33 + (base & 31)];
      dst[0] = v.x; dst[1] = v.y; dst[2] = v.z; dst[3] = v.w;
    }
    __syncthreads();
    const float* wrow = &sWp[u * 3];
    const float* krow = &sK[tid * 33];
#pragma unroll
    for (int g = 0; g < 32; ++g) {
      float v = krow[g];
      a0 = fmaf(v, wrow[g * 54 + 0], a0);
      a1 = fmaf(v, wrow[g * 54 + 1], a1);
      a2 = fmaf(v, wrow[g * 54 + 2], a2);
    }
  }

  float p0 = fmaxf(a0 + bp[0], 0.f);
  float p1 = fmaxf(a1 + bp[1], 0.f);
  float p2 = fmaxf(a2 + bp[2], 0.f);

  float k0 = p0 * Wck[0] + p1 * Wck[3] + p2 * Wck[6] + bck[0];
  float k1 = p0 * Wck[1] + p1 * Wck[4] + p2 * Wck[7] + bck[1];
  float k2 = p0 * Wck[2] + p1 * Wck[5] + p2 * Wck[8] + bck[2];
  float mk = fmaxf(k0, fmaxf(k1, k2));
  float e0 = __expf(k0 - mk), e1 = __expf(k1 - mk), e2 = __expf(k2 - mk);
  float inv = 1.f / (e0 + e1 + e2);
  float ck0 = e0 * inv, ck1 = e1 * inv, ck2 = e2 * inv;

  float q0 = p0 * Wcq[0] + p1 * Wcq[3] + p2 * Wcq[6] + bcq[0];
  float q1 = p0 * Wcq[1] + p1 * Wcq[4] + p2 * Wcq[7] + bcq[1];
  float q2 = p0 * Wcq[2] + p1 * Wcq[5] + p2 * Wcq[8] + bcq[2];
  float mq = fmaxf(q0, fmaxf(q1, q2));
  float f0 = __expf(q0 - mq), f1 = __expf(q1 - mq), f2 = __expf(q2 - mq);
  float invq = 1.f / (f0 + f1 + f2);
  float cq0 = f0 * invq, cq1 = f1 * invq, cq2 = f2 * invq;

  size_t t = (size_t)bb * 2304 + s * 256 + tid;
  ck_out[t * 3 + 0] = ck0;
  ck_out[t * 3 + 1] = ck1;
  ck_out[t * 3 + 2] = ck2;
  cq_out[t * 3 + 0] = cq0;
  cq_out[t * 3 + 1] = cq1;
  cq_out[t * 3 + 2] = cq2;

  float mean = (cq0 + cq1 + cq2) * (1.f / 3.f);
  float d0 = cq0 - mean, d1 = cq1 - mean, d2 = cq2 - mean;
  float var = (d0 * d0 + d1 * d1 + d2 * d2) * 0.5f;
  float sd  = sqrtf(var);
  float sig = log1pf(__expf(sd));
  float ls  = logf(sig);

  __syncthreads();
  red[tid] = ls;
  __syncthreads();
  for (int r = 128; r > 0; r >>= 1) {
    if (tid < r) red[tid] += red[tid + r];
    __syncthreads();
  }
  if (tid == 0) atomicAdd(loss_acc, red[0]);
}

// ---------------------------------------------------------------------------
// K3: FUSED center+prepC (block = (bb,hh,mt) owning lk2 pair L0=hh*16+mt,
// L0+8): two 18x18 causal attentions + Wb relu + disjoint maxpool into LDS,
// pairwise sum, emit Cfrag bf16 directly. ccpool never materializes.
// ---------------------------------------------------------------------------
__global__ __launch_bounds__(256) void center2_kernel(
    const float* __restrict__ cq, const float* __restrict__ ck,
    const float* __restrict__ Wb, const float* __restrict__ bbias,
    uint4* __restrict__ Cfrag) {
  int bid = blockIdx.x;                 // (bb*8+hh)*8+mt
  int mt = bid & 7, hh = (bid >> 3) & 7, bb = bid >> 6;
  int L0 = hh * 16 + mt;
  int tid = threadIdx.x;

  __shared__ float sWb[1728];
  __shared__ float sbb[576];
  __shared__ float scq[2][54], sck[2][54], sq2[2][54];
  __shared__ float pooled[2][1152];

  for (int i = tid; i < 1728; i += 256) sWb[i] = Wb[i];
  for (int i = tid; i < 576; i += 256) sbb[i] = bbias[i];
  if (tid < 108) {
    int h2 = tid / 54, r = tid % 54;
    int Lx = L0 + h2 * 8;
    const float* cqb = cq + ((size_t)bb * 2304 + Lx * 18) * 3;
    const float* ckb = ck + ((size_t)bb * 2304 + Lx * 18) * 3;
    scq[h2][r] = cqb[r];
    sck[h2][r] = ckb[r];
  }
  __syncthreads();

  {
    int h2 = tid >> 6;
    int p  = tid & 63;
    if (h2 < 2 && p < B2) {
      float s[B2];
      float g0 = scq[h2][p * 3 + 0], g1 = scq[h2][p * 3 + 1], g2 = scq[h2][p * 3 + 2];
      float mx = -INFINITY;
#pragma unroll
      for (int u = 0; u < B2; ++u) {
        float sv = (g0 * sck[h2][u * 3] + g1 * sck[h2][u * 3 + 1] +
                    g2 * sck[h2][u * 3 + 2]) * (1.f / 3.f);
        if (u > p) sv = -1e9f;
        s[u] = sv;
        mx = fmaxf(mx, sv);
      }
      float sum = 0.f;
#pragma unroll
      for (int u = 0; u < B2; ++u) { s[u] = __expf(s[u] - mx); sum += s[u]; }
      float inv = 1.f / sum;
      float o0 = 0.f, o1 = 0.f, o2 = 0.f;
#pragma unroll
      for (int u = 0; u < B2; ++u) {
        float a = s[u] * inv;
        o0 = fmaf(a, scq[h2][u * 3 + 0], o0);
        o1 = fmaf(a, scq[h2][u * 3 + 1], o1);
        o2 = fmaf(a, scq[h2][u * 3 + 2], o2);
      }
      sq2[h2][p * 3 + 0] = o0; sq2[h2][p * 3 + 1] = o1; sq2[h2][p * 3 + 2] = o2;
    }
  }
  __syncthreads();

  for (int i = tid; i < 2 * 1152; i += 256) {
    int h2 = i / 1152, r = i % 1152;
    int p = r >> 6, w = r & 63;
    float g0 = sq2[h2][p * 3 + 0], g1 = sq2[h2][p * 3 + 1], g2 = sq2[h2][p * 3 + 2];
    int t0 = w * 9 - 4;
    int lo = t0 < 0 ? 0 : t0;
    int hi = t0 + 8; if (hi > 575) hi = 575;
    float mxv = -INFINITY;
    for (int tt = lo; tt <= hi; ++tt) {
      float cv = g0 * sWb[tt] + g1 * sWb[576 + tt] + g2 * sWb[1152 + tt] + sbb[tt];
      cv = fmaxf(cv, 0.f);
      mxv = fmaxf(mxv, cv);
    }
    pooled[h2][r] = mxv;
  }
  __syncthreads();

  if (tid < 192) {
    int ks = tid >> 6, lane = tid & 63;
    int kk = lane & 15;
    int d0 = ks * 32 + ((lane >> 4) << 3);
    unsigned short hi8[8];
#pragma unroll
    for (int j = 0; j < 8; ++j) {
      int d = d0 + j;
      float v = 0.f;
      if (d < 72) {
        int idx = kk * 72 + d;
        v = pooled[0][idx] + pooled[1][idx];
      }
      hi8[j] = bf16_rne(v);
    }
    uint4 h4;
    h4.x = hi8[0] | (hi8[1] << 16); h4.y = hi8[2] | (hi8[3] << 16);
    h4.z = hi8[4] | (hi8[5] << 16); h4.w = hi8[6] | (hi8[7] << 16);
    int bh = bb * 8 + hh;
    Cfrag[(((size_t)bh * 8 + mt) * 3 + ks) * 64 + lane] = h4;
  }
}

// ---------------------------------------------------------------------------
// K4: MFMA attention (R8-proven config) + loss finalize (block 0).
// ---------------------------------------------------------------------------
__global__ __launch_bounds__(256) void attn2_kernel(
    const float* __restrict__ Q, const uint4* __restrict__ Cfrag,
    const uint4* __restrict__ Vfrag, float* __restrict__ out,
    const float* __restrict__ loss_acc, float* __restrict__ out_loss) {
  __shared__ __align__(16) uint4 sFrag[2816];   // 44 KB: C [0,1536) V [1536,2816)

  if (blockIdx.x == 0 && threadIdx.x == 0)
    *out_loss = loss_acc[0] * (1.f / 82944.f) + 207.93889646f;

  int bh = blockIdx.x / 9, qt = blockIdx.x % 9;
  int tid = threadIdx.x;
  int wid = tid >> 6, lane = tid & 63;
  int lq = lane & 15, lg = lane >> 4;
  int qbase = qt * 128 + wid * 32;

  const uint4* gC = Cfrag + (size_t)bh * 1536;
  const uint4* gV = Vfrag + (size_t)bh * 1280;
#pragma unroll
  for (int k = 0; k < 6; ++k) sFrag[tid + k * 256] = gC[tid + k * 256];
#pragma unroll
  for (int k = 0; k < 5; ++k) sFrag[1536 + tid + k * 256] = gV[tid + k * 256];
  __syncthreads();

  f32x4 sacc[2][8];
#pragma unroll
  for (int s = 0; s < 2; ++s)
#pragma unroll
    for (int mt = 0; mt < 8; ++mt) sacc[s][mt] = (f32x4){0.f, 0.f, 0.f, 0.f};

  // ---- S^T = C * Q^T (bf16 Q) ----
#pragma unroll
  for (int ks = 0; ks < 3; ++ks) {
    short8 qh[2];
#pragma unroll
    for (int s = 0; s < 2; ++s) {
      int q = qbase + s * 16 + lq;
      const float* qrow = Q + ((size_t)bh * L + q) * DK;
      int d0 = ks * 32 + lg * 8;
      float x[8];
      if (ks < 2) {
        float4 a = *(const float4*)(qrow + d0);
        float4 b = *(const float4*)(qrow + d0 + 4);
        x[0] = a.x; x[1] = a.y; x[2] = a.z; x[3] = a.w;
        x[4] = b.x; x[5] = b.y; x[6] = b.z; x[7] = b.w;
      } else {
        if (lg == 0) {
          float4 a = *(const float4*)(qrow + 64);
          float4 b = *(const float4*)(qrow + 68);
          x[0] = a.x; x[1] = a.y; x[2] = a.z; x[3] = a.w;
          x[4] = b.x; x[5] = b.y; x[6] = b.z; x[7] = b.w;
        } else {
#pragma unroll
          for (int j = 0; j < 8; ++j) x[j] = 0.f;
        }
      }
#pragma unroll
      for (int j = 0; j < 8; ++j) qh[s][j] = (short)bf16_rne(x[j]);
    }
#pragma unroll
    for (int mt = 0; mt < 8; ++mt) {
      short8 chi = *(const short8*)&sFrag[(mt * 3 + ks) * 64 + lane];
#pragma unroll
      for (int s = 0; s < 2; ++s)
        sacc[s][mt] = __builtin_amdgcn_mfma_f32_16x16x32_bf16(chi, qh[s], sacc[s][mt], 0, 0, 0);
    }
  }

  // ---- softmax over keys (per q-col), normalized P packed as bf16 pairs ----
  unsigned pw[2][8][2];
#pragma unroll
  for (int s = 0; s < 2; ++s) {
    float mx = -INFINITY;
#pragma unroll
    for (int mt = 0; mt < 8; ++mt)
#pragma unroll
      for (int r = 0; r < 4; ++r) mx = fmaxf(mx, sacc[s][mt][r]);
    mx = fmaxf(mx, __shfl_xor(mx, 16));
    mx = fmaxf(mx, __shfl_xor(mx, 32));
    float sum = 0.f;
#pragma unroll
    for (int mt = 0; mt < 8; ++mt)
#pragma unroll
      for (int r = 0; r < 4; ++r) {
        float p = __expf(sacc[s][mt][r] - mx);
        sacc[s][mt][r] = p;
        sum += p;
      }
    sum += __shfl_xor(sum, 16);
    sum += __shfl_xor(sum, 32);
    float inv = 1.f / sum;
#pragma unroll
    for (int mt = 0; mt < 8; ++mt) {
      pw[s][mt][0] = pack2(sacc[s][mt][0] * inv, sacc[s][mt][1] * inv);
      pw[s][mt][1] = pack2(sacc[s][mt][2] * inv, sacc[s][mt][3] * inv);
    }
  }

  // ---- O = P * V via shfl transpose ----
  f32x4 oacc[2][5];
#pragma unroll
  for (int s = 0; s < 2; ++s)
#pragma unroll
    for (int nt = 0; nt < 5; ++nt) oacc[s][nt] = (f32x4){0.f, 0.f, 0.f, 0.f};

  int baseA = lq + 32 * (lg & 1);
  int baseB = baseA + 16;
  bool hiGrp = (lg & 2) != 0;

#pragma unroll
  for (int ks = 0; ks < 4; ++ks) {
    short8 pa[2];
#pragma unroll
    for (int s = 0; s < 2; ++s) {
      unsigned a0 = pw[s][2 * ks][0],     a1 = pw[s][2 * ks][1];
      unsigned b0 = pw[s][2 * ks + 1][0], b1 = pw[s][2 * ks + 1][1];
      unsigned r00 = __shfl(a0, baseA, 64), r10 = __shfl(b0, baseA, 64);
      unsigned r01 = __shfl(a1, baseA, 64), r11 = __shfl(b1, baseA, 64);
      unsigned r02 = __shfl(a0, baseB, 64), r12 = __shfl(b0, baseB, 64);
      unsigned r03 = __shfl(a1, baseB, 64), r13 = __shfl(b1, baseB, 64);
      uint4 u;
      u.x = hiGrp ? r10 : r00;
      u.y = hiGrp ? r11 : r01;
      u.z = hiGrp ? r12 : r02;
      u.w = hiGrp ? r13 : r03;
      pa[s] = *(short8*)&u;
    }
#pragma unroll
    for (int nt = 0; nt < 5; ++nt) {
      short8 vhi = *(const short8*)&sFrag[1536 + (nt * 4 + ks) * 64 + lane];
#pragma unroll
      for (int s = 0; s < 2; ++s)
        oacc[s][nt] = __builtin_amdgcn_mfma_f32_16x16x32_bf16(pa[s], vhi, oacc[s][nt], 0, 0, 0);
    }
  }

  // ---- store: D layout col=lane&15 (d), row=(lane>>4)*4+r (q) ----
#pragma unroll
  for (int s = 0; s < 2; ++s) {
#pragma unroll
    for (int nt = 0; nt < 5; ++nt) {
      int d = nt * 16 + lq;
      if (d < 72) {
        float* orow = out + ((size_t)bh * L + qbase + s * 16 + lg * 4) * DK + d;
#pragma unroll
        for (int r = 0; r < 4; ++r) orow[(size_t)r * DK] = oacc[s][nt][r];
      }
    }
  }
}

extern "C" void kernel_launch(void* const* d_in, const int* in_sizes, int n_in,
                              void* d_out, int out_size, void* d_ws, size_t ws_size,
                              hipStream_t stream) {
  const float* Q    = (const float*)d_in[0];
  const float* Kin  = (const float*)d_in[1];
  const float* Vin  = (const float*)d_in[2];
  const float* Wp   = (const float*)d_in[3];
  const float* bp   = (const float*)d_in[4];
  const float* Wck  = (const float*)d_in[5];
  const float* bck  = (const float*)d_in[6];
  const float* Wcq  = (const float*)d_in[7];
  const float* bcq  = (const float*)d_in[8];
  const float* Wb   = (const float*)d_in[9];
  const float* bbv  = (const float*)d_in[10];
  float* out = (float*)d_out;

  float* ws = (float*)d_ws;
  float* pK       = ws;
  float* cq       = pK + POOL_TOTAL;
  float* ck       = cq + (size_t)CLUS_TOTAL * 3;
  uint4* Cfrag    = (uint4*)(ck + (size_t)CLUS_TOTAL * 3);
  uint4* Vfrag    = Cfrag + (size_t)CFRAG_T;
  float* loss_acc = (float*)(Vfrag + (size_t)VFRAG_T);

  hipMemsetAsync(loss_acc, 0, sizeof(float), stream);
  hipMemsetAsync(Vfrag, 0, (size_t)VFRAG_T * sizeof(uint4), stream);

  pool_kernel<<<2 * (BATCH * DM) * 32 / 256, 256, 0, stream>>>(
      Kin, Vin, pK, (uint2*)Vfrag);
  cluster_kernel<<<BATCH * 9, 256, 0, stream>>>(
      pK, Wp, bp, Wck, bck, Wcq, bcq, cq, ck, loss_acc);
  center2_kernel<<<BATCH * 64, 256, 0, stream>>>(cq, ck, Wb, bbv, Cfrag);
  attn2_kernel<<<NBH * 9, 256, 0, stream>>>(
      Q, Cfrag, Vfrag, out, loss_acc, out + CTX_ELEMS);
}

// Round 14
// 171.154 us; speedup vs baseline: 1.1468x; 1.0543x over previous
//
#include <hip/hip_runtime.h>
#include <math.h>

#define BATCH 36
#define H 8
#define L 1152
#define DK 72
#define DM 576
#define LK 128
#define B2 18
#define NC 3

// derived
#define POOL_PER_B (DM*LK)            // 73728
#define POOL_TOTAL (BATCH*POOL_PER_B) // 2654208
#define CLUS_TOTAL (BATCH*LK*B2)      // 82944
#define CTX_ELEMS (BATCH*H*L*DK)      // 23887872
#define NBH (BATCH*H)                 // 288
#define CFRAG_T (NBH*8*3*64)          // 442368
#define VFRAG_T (NBH*5*4*64)          // 368640
#define GROUPS_PER_T ((BATCH*DM)*32)  // 663552
#define POOL_BLOCKS (GROUPS_PER_T/256) // 2592

typedef __attribute__((ext_vector_type(8))) short short8;
typedef __attribute__((ext_vector_type(4))) float f32x4;

// round-to-nearest-even fp32 -> bf16 bits
__device__ __forceinline__ unsigned short bf16_rne(float x) {
  unsigned u = __float_as_uint(x);
  unsigned r = u + 0x7FFFu + ((u >> 16) & 1u);
  return (unsigned short)(r >> 16);
}
__device__ __forceinline__ unsigned pack2(float a, float b) {
  return (unsigned)bf16_rne(a) | ((unsigned)bf16_rne(b) << 16);
}
__device__ __forceinline__ float max9(float x0, float x1, float x2, float x3,
                                      float x4, float x5, float x6, float x7,
                                      float x8) {
  float m0 = fmaxf(fmaxf(x0, x1), x2);
  float m1 = fmaxf(fmaxf(x3, x4), x5);
  float m2 = fmaxf(fmaxf(x6, x7), x8);
  return fmaxf(fmaxf(m0, m1), m2);
}

// shared pool-group body: computes the 4 window maxima for group (row,g)
__device__ __forceinline__ void pool_group(const float* __restrict__ src,
                                           int row, int g,
                                           float& w0, float& w1,
                                           float& w2, float& w3) {
  const float* p = src + (size_t)row * L + g * 36;
  float4 a[9];
#pragma unroll
  for (int k = 0; k < 8; ++k) a[k + 1] = *(const float4*)(p + k * 4);
  a[0] = (g > 0) ? *(const float4*)(p - 4)
                 : make_float4(-INFINITY, -INFINITY, -INFINITY, -INFINITY);
  __builtin_amdgcn_sched_barrier(0);
  w0 = max9(a[0].x, a[0].y, a[0].z, a[0].w,
            a[1].x, a[1].y, a[1].z, a[1].w, a[2].x);
  w1 = max9(a[2].y, a[2].z, a[2].w,
            a[3].x, a[3].y, a[3].z, a[3].w, a[4].x, a[4].y);
  w2 = max9(a[4].z, a[4].w,
            a[5].x, a[5].y, a[5].z, a[5].w, a[6].x, a[6].y, a[6].z);
  w3 = max9(a[6].w,
            a[7].x, a[7].y, a[7].z, a[7].w,
            a[8].x, a[8].y, a[8].z, a[8].w);
}

// ---------------------------------------------------------------------------
// K1: pool the K tensor only -> pK fp32 (cluster's input).
// ---------------------------------------------------------------------------
__global__ __launch_bounds__(256, 8) void poolk_kernel(
    const float* __restrict__ Kin, float* __restrict__ pK) {
  int t = blockIdx.x * 256 + threadIdx.x;
  int row = t >> 5, g = t & 31;
  float w0, w1, w2, w3;
  pool_group(Kin, row, g, w0, w1, w2, w3);
  *(float4*)(pK + (size_t)row * LK + g * 4) = make_float4(w0, w1, w2, w3);
}

// ---------------------------------------------------------------------------
// K2: FUSED cluster + poolV. cluster consumes only pK; poolV (V -> Vfrag bf16
// MFMA B-fragment layout) is independent until attn2 — so the two block
// populations co-reside and overlap: cluster's serial tap chain hides under
// poolV's memory streaming. Blocks [0,324) = cluster; [324, 324+2592) = poolV.
// Vfrag mapping (per R13): thread (row,g) holds windows k=4g..4g+3 at fixed
// (bh,d); lane=((g&7)>>1)<<4|(d&15), ks=g>>3, half=g&1 -> one aligned uint2.
// d>=72 pad slots pre-zeroed by hipMemsetAsync.
// ---------------------------------------------------------------------------
__global__ __launch_bounds__(256) void cluster_poolv_kernel(
    const float* __restrict__ pK, const float* __restrict__ Vin,
    uint2* __restrict__ Vfrag2,
    const float* __restrict__ Wp,  const float* __restrict__ bp,
    const float* __restrict__ Wck, const float* __restrict__ bck,
    const float* __restrict__ Wcq, const float* __restrict__ bcq,
    float* __restrict__ cq_out, float* __restrict__ ck_out,
    float* __restrict__ loss_acc) {
  int tid = threadIdx.x;

  if (blockIdx.x >= BATCH * 9) {
    // ---- poolV path ----
    int t = (blockIdx.x - BATCH * 9) * 256 + tid;
    int row = t >> 5, g = t & 31;
    float w0, w1, w2, w3;
    pool_group(Vin, row, g, w0, w1, w2, w3);
    int bb = row / DM, m = row % DM;
    int hh = m / DK, d = m % DK;
    int bh = bb * 8 + hh;
    int nt = d >> 4, dl = d & 15;
    int ks = g >> 3, sub = (g & 7) >> 1, half = g & 1;
    int lane = (sub << 4) | dl;
    size_t u4 = (((size_t)bh * 5 + nt) * 4 + ks) * 64 + lane;
    Vfrag2[u4 * 2 + half] = make_uint2(pack2(w0, w1), pack2(w2, w3));
    return;
  }

  // ---- cluster path ----
  int bb = blockIdx.x / 9;
  int s  = blockIdx.x % 9;

  __shared__ float sK[256 * 33];
  __shared__ float sWp[1728];
  __shared__ float red[256];

  for (int i = tid; i < 1728; i += 256) sWp[i] = Wp[i];

  float a0 = 0.f, a1 = 0.f, a2 = 0.f;
  int umin = (bb >= 18) ? 0 : (18 - bb);

  for (int u = umin; u < 18; ++u) {
    int b2 = bb + u - 17;
    __syncthreads();
    const float4* src = (const float4*)(pK + (size_t)b2 * POOL_PER_B + s * 8192);
#pragma unroll
    for (int k = 0; k < 8; ++k) {
      int i = tid + k * 256;
      float4 v = src[i];
      int base = i * 4;
      float* dst = &sK[(base >> 5) * 33 + (base & 31)];
      dst[0] = v.x; dst[1] = v.y; dst[2] = v.z; dst[3] = v.w;
    }
    __syncthreads();
    const float* wrow = &sWp[u * 3];
    const float* krow = &sK[tid * 33];
#pragma unroll
    for (int g = 0; g < 32; ++g) {
      float v = krow[g];
      a0 = fmaf(v, wrow[g * 54 + 0], a0);
      a1 = fmaf(v, wrow[g * 54 + 1], a1);
      a2 = fmaf(v, wrow[g * 54 + 2], a2);
    }
  }

  float p0 = fmaxf(a0 + bp[0], 0.f);
  float p1 = fmaxf(a1 + bp[1], 0.f);
  float p2 = fmaxf(a2 + bp[2], 0.f);

  float k0 = p0 * Wck[0] + p1 * Wck[3] + p2 * Wck[6] + bck[0];
  float k1 = p0 * Wck[1] + p1 * Wck[4] + p2 * Wck[7] + bck[1];
  float k2 = p0 * Wck[2] + p1 * Wck[5] + p2 * Wck[8] + bck[2];
  float mk = fmaxf(k0, fmaxf(k1, k2));
  float e0 = __expf(k0 - mk), e1 = __expf(k1 - mk), e2 = __expf(k2 - mk);
  float inv = 1.f / (e0 + e1 + e2);
  float ck0 = e0 * inv, ck1 = e1 * inv, ck2 = e2 * inv;

  float q0 = p0 * Wcq[0] + p1 * Wcq[3] + p2 * Wcq[6] + bcq[0];
  float q1 = p0 * Wcq[1] + p1 * Wcq[4] + p2 * Wcq[7] + bcq[1];
  float q2 = p0 * Wcq[2] + p1 * Wcq[5] + p2 * Wcq[8] + bcq[2];
  float mq = fmaxf(q0, fmaxf(q1, q2));
  float f0 = __expf(q0 - mq), f1 = __expf(q1 - mq), f2 = __expf(q2 - mq);
  float invq = 1.f / (f0 + f1 + f2);
  float cq0 = f0 * invq, cq1 = f1 * invq, cq2 = f2 * invq;

  size_t t = (size_t)bb * 2304 + s * 256 + tid;
  ck_out[t * 3 + 0] = ck0;
  ck_out[t * 3 + 1] = ck1;
  ck_out[t * 3 + 2] = ck2;
  cq_out[t * 3 + 0] = cq0;
  cq_out[t * 3 + 1] = cq1;
  cq_out[t * 3 + 2] = cq2;

  float mean = (cq0 + cq1 + cq2) * (1.f / 3.f);
  float d0 = cq0 - mean, d1 = cq1 - mean, d2 = cq2 - mean;
  float var = (d0 * d0 + d1 * d1 + d2 * d2) * 0.5f;
  float sd  = sqrtf(var);
  float sig = log1pf(__expf(sd));
  float ls  = logf(sig);

  __syncthreads();
  red[tid] = ls;
  __syncthreads();
  for (int r = 128; r > 0; r >>= 1) {
    if (tid < r) red[tid] += red[tid + r];
    __syncthreads();
  }
  if (tid == 0) atomicAdd(loss_acc, red[0]);
}

// ---------------------------------------------------------------------------
// K3: FUSED center+prepC (block = (bb,hh,mt) owning lk2 pair L0=hh*16+mt,
// L0+8): two 18x18 causal attentions + Wb relu + disjoint maxpool into LDS,
// pairwise sum, emit Cfrag bf16 directly.
// ---------------------------------------------------------------------------
__global__ __launch_bounds__(256) void center2_kernel(
    const float* __restrict__ cq, const float* __restrict__ ck,
    const float* __restrict__ Wb, const float* __restrict__ bbias,
    uint4* __restrict__ Cfrag) {
  int bid = blockIdx.x;                 // (bb*8+hh)*8+mt
  int mt = bid & 7, hh = (bid >> 3) & 7, bb = bid >> 6;
  int L0 = hh * 16 + mt;
  int tid = threadIdx.x;

  __shared__ float sWb[1728];
  __shared__ float sbb[576];
  __shared__ float scq[2][54], sck[2][54], sq2[2][54];
  __shared__ float pooled[2][1152];

  for (int i = tid; i < 1728; i += 256) sWb[i] = Wb[i];
  for (int i = tid; i < 576; i += 256) sbb[i] = bbias[i];
  if (tid < 108) {
    int h2 = tid / 54, r = tid % 54;
    int Lx = L0 + h2 * 8;
    const float* cqb = cq + ((size_t)bb * 2304 + Lx * 18) * 3;
    const float* ckb = ck + ((size_t)bb * 2304 + Lx * 18) * 3;
    scq[h2][r] = cqb[r];
    sck[h2][r] = ckb[r];
  }
  __syncthreads();

  {
    int h2 = tid >> 6;
    int p  = tid & 63;
    if (h2 < 2 && p < B2) {
      float s[B2];
      float g0 = scq[h2][p * 3 + 0], g1 = scq[h2][p * 3 + 1], g2 = scq[h2][p * 3 + 2];
      float mx = -INFINITY;
#pragma unroll
      for (int u = 0; u < B2; ++u) {
        float sv = (g0 * sck[h2][u * 3] + g1 * sck[h2][u * 3 + 1] +
                    g2 * sck[h2][u * 3 + 2]) * (1.f / 3.f);
        if (u > p) sv = -1e9f;
        s[u] = sv;
        mx = fmaxf(mx, sv);
      }
      float sum = 0.f;
#pragma unroll
      for (int u = 0; u < B2; ++u) { s[u] = __expf(s[u] - mx); sum += s[u]; }
      float inv = 1.f / sum;
      float o0 = 0.f, o1 = 0.f, o2 = 0.f;
#pragma unroll
      for (int u = 0; u < B2; ++u) {
        float a = s[u] * inv;
        o0 = fmaf(a, scq[h2][u * 3 + 0], o0);
        o1 = fmaf(a, scq[h2][u * 3 + 1], o1);
        o2 = fmaf(a, scq[h2][u * 3 + 2], o2);
      }
      sq2[h2][p * 3 + 0] = o0; sq2[h2][p * 3 + 1] = o1; sq2[h2][p * 3 + 2] = o2;
    }
  }
  __syncthreads();

  for (int i = tid; i < 2 * 1152; i += 256) {
    int h2 = i / 1152, r = i % 1152;
    int p = r >> 6, w = r & 63;
    float g0 = sq2[h2][p * 3 + 0], g1 = sq2[h2][p * 3 + 1], g2 = sq2[h2][p * 3 + 2];
    int t0 = w * 9 - 4;
    int lo = t0 < 0 ? 0 : t0;
    int hi = t0 + 8; if (hi > 575) hi = 575;
    float mxv = -INFINITY;
    for (int tt = lo; tt <= hi; ++tt) {
      float cv = g0 * sWb[tt] + g1 * sWb[576 + tt] + g2 * sWb[1152 + tt] + sbb[tt];
      cv = fmaxf(cv, 0.f);
      mxv = fmaxf(mxv, cv);
    }
    pooled[h2][r] = mxv;
  }
  __syncthreads();

  if (tid < 192) {
    int ks = tid >> 6, lane = tid & 63;
    int kk = lane & 15;
    int d0 = ks * 32 + ((lane >> 4) << 3);
    unsigned short hi8[8];
#pragma unroll
    for (int j = 0; j < 8; ++j) {
      int d = d0 + j;
      float v = 0.f;
      if (d < 72) {
        int idx = kk * 72 + d;
        v = pooled[0][idx] + pooled[1][idx];
      }
      hi8[j] = bf16_rne(v);
    }
    uint4 h4;
    h4.x = hi8[0] | (hi8[1] << 16); h4.y = hi8[2] | (hi8[3] << 16);
    h4.z = hi8[4] | (hi8[5] << 16); h4.w = hi8[6] | (hi8[7] << 16);
    int bh = bb * 8 + hh;
    Cfrag[(((size_t)bh * 8 + mt) * 3 + ks) * 64 + lane] = h4;
  }
}

// ---------------------------------------------------------------------------
// K4: MFMA attention (R8-proven config) + loss finalize (block 0).
// ---------------------------------------------------------------------------
__global__ __launch_bounds__(256) void attn2_kernel(
    const float* __restrict__ Q, const uint4* __restrict__ Cfrag,
    const uint4* __restrict__ Vfrag, float* __restrict__ out,
    const float* __restrict__ loss_acc, float* __restrict__ out_loss) {
  __shared__ __align__(16) uint4 sFrag[2816];   // 44 KB: C [0,1536) V [1536,2816)

  if (blockIdx.x == 0 && threadIdx.x == 0)
    *out_loss = loss_acc[0] * (1.f / 82944.f) + 207.93889646f;

  int bh = blockIdx.x / 9, qt = blockIdx.x % 9;
  int tid = threadIdx.x;
  int wid = tid >> 6, lane = tid & 63;
  int lq = lane & 15, lg = lane >> 4;
  int qbase = qt * 128 + wid * 32;

  const uint4* gC = Cfrag + (size_t)bh * 1536;
  const uint4* gV = Vfrag + (size_t)bh * 1280;
#pragma unroll
  for (int k = 0; k < 6; ++k) sFrag[tid + k * 256] = gC[tid + k * 256];
#pragma unroll
  for (int k = 0; k < 5; ++k) sFrag[1536 + tid + k * 256] = gV[tid + k * 256];
  __syncthreads();

  f32x4 sacc[2][8];
#pragma unroll
  for (int s = 0; s < 2; ++s)
#pragma unroll
    for (int mt = 0; mt < 8; ++mt) sacc[s][mt] = (f32x4){0.f, 0.f, 0.f, 0.f};

  // ---- S^T = C * Q^T (bf16 Q) ----
#pragma unroll
  for (int ks = 0; ks < 3; ++ks) {
    short8 qh[2];
#pragma unroll
    for (int s = 0; s < 2; ++s) {
      int q = qbase + s * 16 + lq;
      const float* qrow = Q + ((size_t)bh * L + q) * DK;
      int d0 = ks * 32 + lg * 8;
      float x[8];
      if (ks < 2) {
        float4 a = *(const float4*)(qrow + d0);
        float4 b = *(const float4*)(qrow + d0 + 4);
        x[0] = a.x; x[1] = a.y; x[2] = a.z; x[3] = a.w;
        x[4] = b.x; x[5] = b.y; x[6] = b.z; x[7] = b.w;
      } else {
        if (lg == 0) {
          float4 a = *(const float4*)(qrow + 64);
          float4 b = *(const float4*)(qrow + 68);
          x[0] = a.x; x[1] = a.y; x[2] = a.z; x[3] = a.w;
          x[4] = b.x; x[5] = b.y; x[6] = b.z; x[7] = b.w;
        } else {
#pragma unroll
          for (int j = 0; j < 8; ++j) x[j] = 0.f;
        }
      }
#pragma unroll
      for (int j = 0; j < 8; ++j) qh[s][j] = (short)bf16_rne(x[j]);
    }
#pragma unroll
    for (int mt = 0; mt < 8; ++mt) {
      short8 chi = *(const short8*)&sFrag[(mt * 3 + ks) * 64 + lane];
#pragma unroll
      for (int s = 0; s < 2; ++s)
        sacc[s][mt] = __builtin_amdgcn_mfma_f32_16x16x32_bf16(chi, qh[s], sacc[s][mt], 0, 0, 0);
    }
  }

  // ---- softmax over keys (per q-col), normalized P packed as bf16 pairs ----
  unsigned pw[2][8][2];
#pragma unroll
  for (int s = 0; s < 2; ++s) {
    float mx = -INFINITY;
#pragma unroll
    for (int mt = 0; mt < 8; ++mt)
#pragma unroll
      for (int r = 0; r < 4; ++r) mx = fmaxf(mx, sacc[s][mt][r]);
    mx = fmaxf(mx, __shfl_xor(mx, 16));
    mx = fmaxf(mx, __shfl_xor(mx, 32));
    float sum = 0.f;
#pragma unroll
    for (int mt = 0; mt < 8; ++mt)
#pragma unroll
      for (int r = 0; r < 4; ++r) {
        float p = __expf(sacc[s][mt][r] - mx);
        sacc[s][mt][r] = p;
        sum += p;
      }
    sum += __shfl_xor(sum, 16);
    sum += __shfl_xor(sum, 32);
    float inv = 1.f / sum;
#pragma unroll
    for (int mt = 0; mt < 8; ++mt) {
      pw[s][mt][0] = pack2(sacc[s][mt][0] * inv, sacc[s][mt][1] * inv);
      pw[s][mt][1] = pack2(sacc[s][mt][2] * inv, sacc[s][mt][3] * inv);
    }
  }

  // ---- O = P * V via shfl transpose ----
  f32x4 oacc[2][5];
#pragma unroll
  for (int s = 0; s < 2; ++s)
#pragma unroll
    for (int nt = 0; nt < 5; ++nt) oacc[s][nt] = (f32x4){0.f, 0.f, 0.f, 0.f};

  int baseA = lq + 32 * (lg & 1);
  int baseB = baseA + 16;
  bool hiGrp = (lg & 2) != 0;

#pragma unroll
  for (int ks = 0; ks < 4; ++ks) {
    short8 pa[2];
#pragma unroll
    for (int s = 0; s < 2; ++s) {
      unsigned a0 = pw[s][2 * ks][0],     a1 = pw[s][2 * ks][1];
      unsigned b0 = pw[s][2 * ks + 1][0], b1 = pw[s][2 * ks + 1][1];
      unsigned r00 = __shfl(a0, baseA, 64), r10 = __shfl(b0, baseA, 64);
      unsigned r01 = __shfl(a1, baseA, 64), r11 = __shfl(b1, baseA, 64);
      unsigned r02 = __shfl(a0, baseB, 64), r12 = __shfl(b0, baseB, 64);
      unsigned r03 = __shfl(a1, baseB, 64), r13 = __shfl(b1, baseB, 64);
      uint4 u;
      u.x = hiGrp ? r10 : r00;
      u.y = hiGrp ? r11 : r01;
      u.z = hiGrp ? r12 : r02;
      u.w = hiGrp ? r13 : r03;
      pa[s] = *(short8*)&u;
    }
#pragma unroll
    for (int nt = 0; nt < 5; ++nt) {
      short8 vhi = *(const short8*)&sFrag[1536 + (nt * 4 + ks) * 64 + lane];
#pragma unroll
      for (int s = 0; s < 2; ++s)
        oacc[s][nt] = __builtin_amdgcn_mfma_f32_16x16x32_bf16(pa[s], vhi, oacc[s][nt], 0, 0, 0);
    }
  }

  // ---- store: D layout col=lane&15 (d), row=(lane>>4)*4+r (q) ----
#pragma unroll
  for (int s = 0; s < 2; ++s) {
#pragma unroll
    for (int nt = 0; nt < 5; ++nt) {
      int d = nt * 16 + lq;
      if (d < 72) {
        float* orow = out + ((size_t)bh * L + qbase + s * 16 + lg * 4) * DK + d;
#pragma unroll
        for (int r = 0; r < 4; ++r) orow[(size_t)r * DK] = oacc[s][nt][r];
      }
    }
  }
}

extern "C" void kernel_launch(void* const* d_in, const int* in_sizes, int n_in,
                              void* d_out, int out_size, void* d_ws, size_t ws_size,
                              hipStream_t stream) {
  const float* Q    = (const float*)d_in[0];
  const float* Kin  = (const float*)d_in[1];
  const float* Vin  = (const float*)d_in[2];
  const float* Wp   = (const float*)d_in[3];
  const float* bp   = (const float*)d_in[4];
  const float* Wck  = (const float*)d_in[5];
  const float* bck  = (const float*)d_in[6];
  const float* Wcq  = (const float*)d_in[7];
  const float* bcq  = (const float*)d_in[8];
  const float* Wb   = (const float*)d_in[9];
  const float* bbv  = (const float*)d_in[10];
  float* out = (float*)d_out;

  float* ws = (float*)d_ws;
  float* pK       = ws;
  float* cq       = pK + POOL_TOTAL;
  float* ck       = cq + (size_t)CLUS_TOTAL * 3;
  uint4* Cfrag    = (uint4*)(ck + (size_t)CLUS_TOTAL * 3);
  uint4* Vfrag    = Cfrag + (size_t)CFRAG_T;
  float* loss_acc = (float*)(Vfrag + (size_t)VFRAG_T);

  hipMemsetAsync(loss_acc, 0, sizeof(float), stream);
  hipMemsetAsync(Vfrag, 0, (size_t)VFRAG_T * sizeof(uint4), stream);

  poolk_kernel<<<POOL_BLOCKS, 256, 0, stream>>>(Kin, pK);
  cluster_poolv_kernel<<<BATCH * 9 + POOL_BLOCKS, 256, 0, stream>>>(
      pK, Vin, (uint2*)Vfrag, Wp, bp, Wck, bck, Wcq, bcq, cq, ck, loss_acc);
  center2_kernel<<<BATCH * 64, 256, 0, stream>>>(cq, ck, Wb, bbv, Cfrag);
  attn2_kernel<<<NBH * 9, 256, 0, stream>>>(
      Q, Cfrag, Vfrag, out, loss_acc, out + CTX_ELEMS);
}